// Round 1
// baseline (915.105 us; speedup 1.0000x reference)
//
#include <hip/hip_runtime.h>

#define NN 50000
#define NE 800000
#define NG 128

typedef __attribute__((ext_vector_type(8))) short short8;
typedef __attribute__((ext_vector_type(4))) float f32x4;

__device__ __forceinline__ unsigned short f2bf(float f){
  union { float f; unsigned int u; } v; v.f = f;
  return (unsigned short)((v.u + 0x7fffu + ((v.u >> 16) & 1u)) >> 16);
}
__device__ __forceinline__ float bf2f(unsigned short h){
  union { unsigned int u; float f; } v; v.u = ((unsigned int)h) << 16;
  return v.f;
}

// ---------------- CSR build ----------------
__global__ __launch_bounds__(256) void k_count(const int* __restrict__ idx,
                                               int* __restrict__ cnt, int n){
  int i = blockIdx.x*256 + threadIdx.x;
  if (i < n) atomicAdd(&cnt[idx[i]], 1);
}

__global__ __launch_bounds__(256) void k_blocksum(const int* __restrict__ in, int n,
                                                  int* __restrict__ bsum){
  __shared__ int ws4[4];
  int i = blockIdx.x*256 + threadIdx.x;
  int v = (i < n) ? in[i] : 0;
  #pragma unroll
  for (int d=1; d<64; d<<=1) v += __shfl_xor(v, d);
  int lane = threadIdx.x & 63, w = threadIdx.x >> 6;
  if (lane == 0) ws4[w] = v;
  __syncthreads();
  if (threadIdx.x == 0) bsum[blockIdx.x] = ws4[0]+ws4[1]+ws4[2]+ws4[3];
}

// exclusive scan of n<=256 elements, single block of 256; out[n]=total
__global__ __launch_bounds__(256) void k_scan_small(const int* __restrict__ in, int n,
                                                    int* __restrict__ out,
                                                    int* __restrict__ fpos){
  __shared__ int wsum[4];
  int tid = threadIdx.x, lane = tid & 63, w = tid >> 6;
  int v = (tid < n) ? in[tid] : 0;
  int x = v;
  #pragma unroll
  for (int d=1; d<64; d<<=1){ int y = __shfl_up(x, d); if (lane >= d) x += y; }
  if (lane == 63) wsum[w] = x;
  __syncthreads();
  int pre2 = 0;
  for (int j=0; j<w; ++j) pre2 += wsum[j];
  int incl = x + pre2;
  if (tid < n){ out[tid] = incl - v; if (fpos) fpos[tid] = incl - v; }
  if (tid == n-1) out[n] = incl;
}

__global__ __launch_bounds__(256) void k_scan_apply(const int* __restrict__ in, int n,
                                                    const int* __restrict__ boff,
                                                    int* __restrict__ out,
                                                    int* __restrict__ fpos){
  __shared__ int wsum[4];
  int tid = threadIdx.x, lane = tid & 63, w = tid >> 6;
  int i = blockIdx.x*256 + tid;
  int v = (i < n) ? in[i] : 0;
  int x = v;
  #pragma unroll
  for (int d=1; d<64; d<<=1){ int y = __shfl_up(x, d); if (lane >= d) x += y; }
  if (lane == 63) wsum[w] = x;
  __syncthreads();
  int pre2 = boff[blockIdx.x];
  for (int j=0; j<w; ++j) pre2 += wsum[j];
  int excl = x - v + pre2;
  if (i < n){
    out[i] = excl; fpos[i] = excl;
    if (i == n-1) out[n] = excl + v;
  }
}

__global__ __launch_bounds__(256) void k_fill(const int* __restrict__ src,
                                              const int* __restrict__ dst,
                                              int* __restrict__ fpos,
                                              int* __restrict__ csr, int n){
  int i = blockIdx.x*256 + threadIdx.x;
  if (i < n){
    int p = atomicAdd(&fpos[dst[i]], 1);
    csr[p] = src[i];
  }
}

// ---------------- weight pre-transpose to bf16 ----------------
// Wt layout per layer: [256 rows][64 k] bf16; rows 0..63=q cols, 64..127=k, 128..191=v, 192..255=o
__global__ __launch_bounds__(256) void k_wt(const float* __restrict__ Wq,
                                            const float* __restrict__ Wk,
                                            const float* __restrict__ Wv,
                                            const float* __restrict__ Wo,
                                            unsigned short* __restrict__ Wt){
  int gid = blockIdx.x*256 + threadIdx.x;   // 49152 total
  int l   = gid >> 14;
  int rem = gid & 16383;
  int mat = rem >> 12;
  int idx = rem & 4095;
  int c = idx >> 6, n = idx & 63;
  const float* srcp = (mat==0)?Wq:(mat==1)?Wk:(mat==2)?Wv:Wo;
  float v = srcp[l*4096 + idx];
  Wt[l*16384 + (mat*64 + n)*64 + c] = f2bf(v);
}

// ---------------- elementwise fp32 -> bf16 ----------------
__global__ __launch_bounds__(256) void k_f2bf(const float* __restrict__ in,
                                              unsigned short* __restrict__ out){
  int i = blockIdx.x*256 + threadIdx.x;   // one ushort4 per thread
  float4 v = ((const float4*)in)[i];
  ushort4 o; o.x=f2bf(v.x); o.y=f2bf(v.y); o.z=f2bf(v.z); o.w=f2bf(v.w);
  ((ushort4*)out)[i] = o;
}

// ---------------- per-row LN (64) -> bf16 ----------------
__global__ __launch_bounds__(256) void k_ln_bf16(const float* __restrict__ x,
                                                 const float* __restrict__ g,
                                                 const float* __restrict__ b,
                                                 unsigned short* __restrict__ out){
  int w = threadIdx.x >> 6, lane = threadIdx.x & 63;
  int r = (blockIdx.x*4 + w)*4 + (lane >> 4);
  int c4 = lane & 15;
  float4 v = ((const float4*)x)[r*16 + c4];
  float s = v.x+v.y+v.z+v.w;
  float q = v.x*v.x+v.y*v.y+v.z*v.z+v.w*v.w;
  #pragma unroll
  for (int d=1; d<16; d<<=1){ s += __shfl_xor(s, d); q += __shfl_xor(q, d); }
  float mu = s*(1.f/64.f);
  float rs = rsqrtf(q*(1.f/64.f) - mu*mu + 1e-5f);
  float4 gv = ((const float4*)g)[c4], bv = ((const float4*)b)[c4];
  ushort4 o;
  o.x=f2bf((v.x-mu)*rs*gv.x+bv.x); o.y=f2bf((v.y-mu)*rs*gv.y+bv.y);
  o.z=f2bf((v.z-mu)*rs*gv.z+bv.z); o.w=f2bf((v.w-mu)*rs*gv.w+bv.w);
  ((ushort4*)out)[r*16 + c4] = o;
}

// ---------------- relu + LN -> fp32 ----------------
__global__ __launch_bounds__(256) void k_postln(const float* __restrict__ x,
                                                const float* __restrict__ g,
                                                const float* __restrict__ b,
                                                float* __restrict__ out){
  int w = threadIdx.x >> 6, lane = threadIdx.x & 63;
  int r = (blockIdx.x*4 + w)*4 + (lane >> 4);
  int c4 = lane & 15;
  float4 v = ((const float4*)x)[r*16 + c4];
  v.x = fmaxf(v.x, 0.f); v.y = fmaxf(v.y, 0.f);
  v.z = fmaxf(v.z, 0.f); v.w = fmaxf(v.w, 0.f);
  float s = v.x+v.y+v.z+v.w;
  float q = v.x*v.x+v.y*v.y+v.z*v.z+v.w*v.w;
  #pragma unroll
  for (int d=1; d<16; d<<=1){ s += __shfl_xor(s, d); q += __shfl_xor(q, d); }
  float mu = s*(1.f/64.f);
  float rs = rsqrtf(q*(1.f/64.f) - mu*mu + 1e-5f);
  float4 gv = ((const float4*)g)[c4], bv = ((const float4*)b)[c4];
  float4 o = make_float4((v.x-mu)*rs*gv.x+bv.x, (v.y-mu)*rs*gv.y+bv.y,
                         (v.z-mu)*rs*gv.z+bv.z, (v.w-mu)*rs*gv.w+bv.w);
  ((float4*)out)[r*16 + c4] = o;
}

// ---------------- GIN aggregate via CSR gather (bf16 table, fp32 accum) ----------------
__global__ __launch_bounds__(256) void k_aggregate(const unsigned short* __restrict__ pre,
                                                   const int* __restrict__ off,
                                                   const int* __restrict__ csr,
                                                   float* __restrict__ agg){
  int w = threadIdx.x >> 6, lane = threadIdx.x & 63;
  int node = blockIdx.x*4 + w;
  int s = off[node], e = off[node+1];
  const ushort4* base = (const ushort4*)pre;
  ushort4 u = base[node*64 + lane];
  float a0 = bf2f(u.x), a1 = bf2f(u.y), a2 = bf2f(u.z), a3 = bf2f(u.w);
  int i = s;
  for (; i + 4 <= e; i += 4){
    int n0 = csr[i], n1 = csr[i+1], n2 = csr[i+2], n3 = csr[i+3];
    ushort4 u0 = base[n0*64 + lane], u1 = base[n1*64 + lane];
    ushort4 u2 = base[n2*64 + lane], u3 = base[n3*64 + lane];
    a0 += bf2f(u0.x)+bf2f(u1.x)+bf2f(u2.x)+bf2f(u3.x);
    a1 += bf2f(u0.y)+bf2f(u1.y)+bf2f(u2.y)+bf2f(u3.y);
    a2 += bf2f(u0.z)+bf2f(u1.z)+bf2f(u2.z)+bf2f(u3.z);
    a3 += bf2f(u0.w)+bf2f(u1.w)+bf2f(u2.w)+bf2f(u3.w);
  }
  for (; i < e; ++i){
    int n0 = csr[i];
    ushort4 u0 = base[n0*64 + lane];
    a0 += bf2f(u0.x); a1 += bf2f(u0.y); a2 += bf2f(u0.z); a3 += bf2f(u0.w);
  }
  ((float4*)agg)[node*64 + lane] = make_float4(a0, a1, a2, a3);
}

// ---------------- fused SAB: LN -> QKV (MFMA) -> attention(S=4) -> O-proj (MFMA) -> residual ----------------
// one wave = 4 nodes = 16 rows; block = 4 waves = 16 nodes; grid = 3125. No __syncthreads (wave-private LDS).
__global__ __launch_bounds__(256) void k_sab(const float* __restrict__ agg,
                                             float* __restrict__ h,
                                             const unsigned short* __restrict__ Wt,
                                             const float* __restrict__ lng,
                                             const float* __restrict__ lnb,
                                             int residual){
  __shared__ unsigned short xo_s[4][16][72];    // xin (phase1/2) then o (phase3/4), aliased
  __shared__ unsigned short qkv_s[4][16][200];  // cols 0..63 q, 64..127 k, 128..191 v

  int tid = threadIdx.x;
  int w = tid >> 6, lane = tid & 63;
  int c16 = lane & 15, kb = lane >> 4;
  int R0 = blockIdx.x*64 + w*16;   // 16 contiguous global rows (4 nodes)

  // phase 1: LN of agg rows -> bf16 staging
  {
    float4 gv = ((const float4*)lng)[c16];
    float4 bv = ((const float4*)lnb)[c16];
    #pragma unroll
    for (int rr=0; rr<4; ++rr){
      int m = rr*4 + kb;
      float4 v = ((const float4*)agg)[(R0+m)*16 + c16];
      float s = v.x+v.y+v.z+v.w;
      float q = v.x*v.x+v.y*v.y+v.z*v.z+v.w*v.w;
      #pragma unroll
      for (int d=1; d<16; d<<=1){ s += __shfl_xor(s, d); q += __shfl_xor(q, d); }
      float mu = s*(1.f/64.f);
      float rs = rsqrtf(q*(1.f/64.f) - mu*mu + 1e-5f);
      ushort4 o;
      o.x=f2bf((v.x-mu)*rs*gv.x+bv.x); o.y=f2bf((v.y-mu)*rs*gv.y+bv.y);
      o.z=f2bf((v.z-mu)*rs*gv.z+bv.z); o.w=f2bf((v.w-mu)*rs*gv.w+bv.w);
      *(ushort4*)&xo_s[w][m][c16*4] = o;
    }
  }

  // phase 2: QKV = xin @ Wqkv  (A: m=lane&15, k=(lane>>4)*8+j ; B: n=lane&15, same k)
  short8 a0 = *(const short8*)&xo_s[w][c16][kb*8];
  short8 a1 = *(const short8*)&xo_s[w][c16][32 + kb*8];
  f32x4 acc[12];
  #pragma unroll
  for (int t=0; t<12; ++t){
    short8 b0 = *(const short8*)&Wt[(t*16 + c16)*64 + kb*8];
    short8 b1 = *(const short8*)&Wt[(t*16 + c16)*64 + 32 + kb*8];
    f32x4 z = {0.f, 0.f, 0.f, 0.f};
    z = __builtin_amdgcn_mfma_f32_16x16x32_bf16(a0, b0, z, 0, 0, 0);
    z = __builtin_amdgcn_mfma_f32_16x16x32_bf16(a1, b1, z, 0, 0, 0);
    acc[t] = z;
  }
  // C/D layout: col=lane&15, row=(lane>>4)*4+reg
  #pragma unroll
  for (int t=0; t<12; ++t){
    #pragma unroll
    for (int r=0; r<4; ++r)
      qkv_s[w][kb*4 + r][t*16 + c16] = f2bf(acc[t][r]);
  }

  // phase 3: attention, S=4, per (node, head, q-row) lane
  {
    int p = lane >> 2, qr = lane & 3;
    int ns = p >> 2, hd = p & 3;
    int mrow = ns*4 + qr;
    int qc = hd*16, kc = 64 + hd*16, vc = 128 + hd*16;
    float qv[16];
    short8 u0 = *(const short8*)&qkv_s[w][mrow][qc];
    short8 u1 = *(const short8*)&qkv_s[w][mrow][qc+8];
    #pragma unroll
    for (int j=0; j<8; ++j){
      qv[j]   = bf2f((unsigned short)u0[j]);
      qv[8+j] = bf2f((unsigned short)u1[j]);
    }
    float sc[4];
    #pragma unroll
    for (int kr=0; kr<4; ++kr){
      short8 k0 = *(const short8*)&qkv_s[w][ns*4+kr][kc];
      short8 k1 = *(const short8*)&qkv_s[w][ns*4+kr][kc+8];
      float d2 = 0.f;
      #pragma unroll
      for (int j=0; j<8; ++j){
        d2 += qv[j]  *bf2f((unsigned short)k0[j]);
        d2 += qv[8+j]*bf2f((unsigned short)k1[j]);
      }
      sc[kr] = d2 * 0.25f;   // 1/sqrt(16)
    }
    float mx = fmaxf(fmaxf(sc[0],sc[1]), fmaxf(sc[2],sc[3]));
    float e0=__expf(sc[0]-mx), e1=__expf(sc[1]-mx), e2=__expf(sc[2]-mx), e3=__expf(sc[3]-mx);
    float inv = 1.f/(e0+e1+e2+e3);
    float at[4] = {e0*inv, e1*inv, e2*inv, e3*inv};
    float ov[16];
    #pragma unroll
    for (int j=0; j<16; ++j) ov[j] = 0.f;
    #pragma unroll
    for (int kr=0; kr<4; ++kr){
      short8 v0 = *(const short8*)&qkv_s[w][ns*4+kr][vc];
      short8 v1 = *(const short8*)&qkv_s[w][ns*4+kr][vc+8];
      #pragma unroll
      for (int j=0; j<8; ++j){
        ov[j]   += at[kr]*bf2f((unsigned short)v0[j]);
        ov[8+j] += at[kr]*bf2f((unsigned short)v1[j]);
      }
    }
    short8 s0v, s1v;
    #pragma unroll
    for (int j=0; j<8; ++j){
      s0v[j] = (short)f2bf(ov[j]);
      s1v[j] = (short)f2bf(ov[8+j]);
    }
    *(short8*)&xo_s[w][mrow][qc]   = s0v;
    *(short8*)&xo_s[w][mrow][qc+8] = s1v;
  }

  // phase 4: out = o @ Wo  (+ h + agg if residual), write h
  short8 oa0 = *(const short8*)&xo_s[w][c16][kb*8];
  short8 oa1 = *(const short8*)&xo_s[w][c16][32 + kb*8];
  #pragma unroll
  for (int t=0; t<4; ++t){
    short8 b0 = *(const short8*)&Wt[(192 + t*16 + c16)*64 + kb*8];
    short8 b1 = *(const short8*)&Wt[(192 + t*16 + c16)*64 + 32 + kb*8];
    f32x4 z = {0.f, 0.f, 0.f, 0.f};
    z = __builtin_amdgcn_mfma_f32_16x16x32_bf16(oa0, b0, z, 0, 0, 0);
    z = __builtin_amdgcn_mfma_f32_16x16x32_bf16(oa1, b1, z, 0, 0, 0);
    #pragma unroll
    for (int r=0; r<4; ++r){
      int row = kb*4 + r, col = t*16 + c16;
      int gi = (R0+row)*64 + col;
      float val = z[r];
      if (residual) val += h[gi] + agg[gi];
      h[gi] = val;
    }
  }
}

// ---------------- per-graph pooling (graph_ids sorted -> contiguous ranges) ----------------
__global__ __launch_bounds__(256) void k_pool(const float* __restrict__ src,
                                              const int* __restrict__ goff,
                                              float* __restrict__ out){
  int g = blockIdx.x, t = threadIdx.x;
  int s = goff[g], e = goff[g+1];
  float a0=0.f, a1=0.f, a2=0.f, a3=0.f;
  int n = s;
  for (; n + 4 <= e; n += 4){
    a0 += src[n*256 + t];       a1 += src[(n+1)*256 + t];
    a2 += src[(n+2)*256 + t];   a3 += src[(n+3)*256 + t];
  }
  for (; n < e; ++n) a0 += src[n*256 + t];
  out[g*256 + t] = a0+a1+a2+a3;
}

// ---------------- final: score = sum_i pooled_i @ W_pred[i] + b_pred[i] ----------------
__global__ __launch_bounds__(256) void k_final(const float* __restrict__ pooled,
                                               const float* __restrict__ Wp,
                                               const float* __restrict__ bp,
                                               float* __restrict__ out){
  int t = blockIdx.x*256 + threadIdx.x;  // 8192 = 128*4*16
  int b = t >> 6, s = (t >> 4) & 3, o = t & 15;
  float acc = 0.f;
  for (int i=0; i<4; ++i){
    acc += bp[i*16 + o];
    const float* pr = pooled + i*32768 + b*256 + s*64;
    const float* wp = Wp + i*1024 + o;
    float a = 0.f;
    #pragma unroll 8
    for (int c=0; c<64; ++c) a += pr[c]*wp[c*16];
    acc += a;
  }
  out[t] = acc;
}

// ---------------- workspace layout (bytes) ----------------
static const size_t OFF_H    = 0;           // fp32 [50000*256]
static const size_t OFF_AGG  = 51200000;    // fp32 [50000*256] (doubles as rbuf after SAB)
static const size_t OFF_PRE  = 102400000;   // bf16 [50000*256]
static const size_t OFF_CSR  = 128000000;   // int [800000]
static const size_t OFF_CNT  = 131200000;   // int [50000]
static const size_t OFF_OFF  = 131400064;   // int [50001]
static const size_t OFF_FPOS = 131600128;   // int [50000]
static const size_t OFF_GCNT = 131800192;   // int [128]
static const size_t OFF_GOFF = 131800768;   // int [129]
static const size_t OFF_GFIL = 131801344;   // int [128]
static const size_t OFF_POOL = 131801920;   // fp32 [4][128*256]
static const size_t OFF_WT   = 132326208;   // bf16 [3][256*64]
static const size_t OFF_BSUM = 132424576;   // int [196]
static const size_t OFF_BOFF = 132425472;   // int [197]

extern "C" void kernel_launch(void* const* d_in, const int* in_sizes, int n_in,
                              void* d_out, int out_size, void* d_ws, size_t ws_size,
                              hipStream_t stream) {
  const float* feat = (const float*)d_in[0];
  const int*   src  = (const int*)d_in[1];
  const int*   dst  = (const int*)d_in[2];
  const int*   gid  = (const int*)d_in[3];
  const float* Wq   = (const float*)d_in[4];
  const float* Wk   = (const float*)d_in[5];
  const float* Wv   = (const float*)d_in[6];
  const float* Wo   = (const float*)d_in[7];
  const float* sg   = (const float*)d_in[8];
  const float* sb   = (const float*)d_in[9];
  const float* l1g  = (const float*)d_in[10];
  const float* l1b  = (const float*)d_in[11];
  const float* l2g  = (const float*)d_in[12];
  const float* l2b  = (const float*)d_in[13];
  const float* Wp   = (const float*)d_in[14];
  const float* bp   = (const float*)d_in[15];
  float* out = (float*)d_out;

  char* ws = (char*)d_ws;
  float*          h      = (float*)(ws + OFF_H);
  float*          agg    = (float*)(ws + OFF_AGG);
  unsigned short* pre    = (unsigned short*)(ws + OFF_PRE);
  int*            csr    = (int*)(ws + OFF_CSR);
  int*            cnt    = (int*)(ws + OFF_CNT);
  int*            off    = (int*)(ws + OFF_OFF);
  int*            fpos   = (int*)(ws + OFF_FPOS);
  int*            gcnt   = (int*)(ws + OFF_GCNT);
  int*            goff   = (int*)(ws + OFF_GOFF);
  int*            gfil   = (int*)(ws + OFF_GFIL);
  float*          pooled = (float*)(ws + OFF_POOL);
  unsigned short* Wt     = (unsigned short*)(ws + OFF_WT);
  int*            bsum   = (int*)(ws + OFF_BSUM);
  int*            boff   = (int*)(ws + OFF_BOFF);

  hipMemsetAsync(cnt, 0, NN*sizeof(int), stream);
  hipMemsetAsync(gcnt, 0, NG*sizeof(int), stream);

  // CSR for dst; graph offsets (graph_ids sorted)
  k_count<<<NE/256, 256, 0, stream>>>(dst, cnt, NE);
  k_count<<<(NN+255)/256, 256, 0, stream>>>(gid, gcnt, NN);
  k_blocksum<<<196, 256, 0, stream>>>(cnt, NN, bsum);
  k_scan_small<<<1, 256, 0, stream>>>(bsum, 196, boff, (int*)0);
  k_scan_small<<<1, 256, 0, stream>>>(gcnt, NG, goff, gfil);
  k_scan_apply<<<196, 256, 0, stream>>>(cnt, NN, boff, off, fpos);
  k_fill<<<NE/256, 256, 0, stream>>>(src, dst, fpos, csr, NE);

  // weights transpose + feat->bf16 + hidden_rep[0] pooling
  k_wt<<<192, 256, 0, stream>>>(Wq, Wk, Wv, Wo, Wt);
  k_f2bf<<<12500, 256, 0, stream>>>(feat, pre);
  k_pool<<<NG, 256, 0, stream>>>(feat, goff, pooled + 0*32768);

  // layer 0: agg = feat + segsum(feat[src]); h = SAB(agg) (no residual)
  k_aggregate<<<12500, 256, 0, stream>>>(pre, off, csr, agg);
  k_sab<<<3125, 256, 0, stream>>>(agg, h, Wt + 0*16384, sg + 0, sb + 0, 0);
  k_postln<<<12500, 256, 0, stream>>>(h, l2g + 0, l2b + 0, agg);
  k_pool<<<NG, 256, 0, stream>>>(agg, goff, pooled + 1*32768);

  // layers 1,2
  for (int i = 1; i < 3; ++i){
    k_ln_bf16<<<12500, 256, 0, stream>>>(h, l1g + i*64, l1b + i*64, pre);
    k_aggregate<<<12500, 256, 0, stream>>>(pre, off, csr, agg);
    k_sab<<<3125, 256, 0, stream>>>(agg, h, Wt + i*16384, sg + i*64, sb + i*64, 1);
    k_postln<<<12500, 256, 0, stream>>>(h, l2g + i*64, l2b + i*64, agg);
    k_pool<<<NG, 256, 0, stream>>>(agg, goff, pooled + (i+1)*32768);
  }

  k_final<<<32, 256, 0, stream>>>(pooled, Wp, bp, out);
}

// Round 2
// 817.218 us; speedup vs baseline: 1.1198x; 1.1198x over previous
//
#include <hip/hip_runtime.h>

#define NN 50000
#define NE 800000
#define NG 128
#define RREP 16
#define RSTRIDE 50048

typedef __attribute__((ext_vector_type(8))) short short8;
typedef __attribute__((ext_vector_type(4))) float f32x4;

__device__ __forceinline__ unsigned short f2bf(float f){
  union { float f; unsigned int u; } v; v.f = f;
  return (unsigned short)((v.u + 0x7fffu + ((v.u >> 16) & 1u)) >> 16);
}
__device__ __forceinline__ float bf2f(unsigned short h){
  union { unsigned int u; float f; } v; v.u = ((unsigned int)h) << 16;
  return v.f;
}

// ---------------- CSR build (16-way replicated histograms to kill atomic line contention) ----------------
__global__ __launch_bounds__(256) void k_count_rep(const int* __restrict__ idx,
                                                   int* __restrict__ cnt_rep, int n){
  int i = blockIdx.x*256 + threadIdx.x;
  int r = blockIdx.x & (RREP-1);
  if (i < n) atomicAdd(&cnt_rep[r*RSTRIDE + idx[i]], 1);
}

__global__ __launch_bounds__(256) void k_count(const int* __restrict__ idx,
                                               int* __restrict__ cnt, int n){
  int i = blockIdx.x*256 + threadIdx.x;
  if (i < n) atomicAdd(&cnt[idx[i]], 1);
}

__global__ __launch_bounds__(256) void k_reduce_rep(const int* __restrict__ cnt_rep,
                                                    int* __restrict__ cnt){
  int i = blockIdx.x*256 + threadIdx.x;
  if (i < NN){
    int s = 0;
    #pragma unroll
    for (int r=0; r<RREP; ++r) s += cnt_rep[r*RSTRIDE + i];
    cnt[i] = s;
  }
}

__global__ __launch_bounds__(256) void k_blocksum(const int* __restrict__ in, int n,
                                                  int* __restrict__ bsum){
  __shared__ int ws4[4];
  int i = blockIdx.x*256 + threadIdx.x;
  int v = (i < n) ? in[i] : 0;
  #pragma unroll
  for (int d=1; d<64; d<<=1) v += __shfl_xor(v, d);
  int lane = threadIdx.x & 63, w = threadIdx.x >> 6;
  if (lane == 0) ws4[w] = v;
  __syncthreads();
  if (threadIdx.x == 0) bsum[blockIdx.x] = ws4[0]+ws4[1]+ws4[2]+ws4[3];
}

// exclusive scan of n<=256 elements, single block of 256; out[n]=total
__global__ __launch_bounds__(256) void k_scan_small(const int* __restrict__ in, int n,
                                                    int* __restrict__ out,
                                                    int* __restrict__ fpos){
  __shared__ int wsum[4];
  int tid = threadIdx.x, lane = tid & 63, w = tid >> 6;
  int v = (tid < n) ? in[tid] : 0;
  int x = v;
  #pragma unroll
  for (int d=1; d<64; d<<=1){ int y = __shfl_up(x, d); if (lane >= d) x += y; }
  if (lane == 63) wsum[w] = x;
  __syncthreads();
  int pre2 = 0;
  for (int j=0; j<w; ++j) pre2 += wsum[j];
  int incl = x + pre2;
  if (tid < n){ out[tid] = incl - v; if (fpos) fpos[tid] = incl - v; }
  if (tid == n-1) out[n] = incl;
}

__global__ __launch_bounds__(256) void k_scan_apply(const int* __restrict__ in, int n,
                                                    const int* __restrict__ boff,
                                                    int* __restrict__ out){
  __shared__ int wsum[4];
  int tid = threadIdx.x, lane = tid & 63, w = tid >> 6;
  int i = blockIdx.x*256 + tid;
  int v = (i < n) ? in[i] : 0;
  int x = v;
  #pragma unroll
  for (int d=1; d<64; d<<=1){ int y = __shfl_up(x, d); if (lane >= d) x += y; }
  if (lane == 63) wsum[w] = x;
  __syncthreads();
  int pre2 = boff[blockIdx.x];
  for (int j=0; j<w; ++j) pre2 += wsum[j];
  int excl = x - v + pre2;
  if (i < n){
    out[i] = excl;
    if (i == n-1) out[n] = excl + v;
  }
}

// per-replica fill cursors: fpos_rep[r][n] = off[n] + sum_{j<r} cnt_rep[j][n]
__global__ __launch_bounds__(256) void k_fpos_rep(const int* __restrict__ cnt_rep,
                                                  const int* __restrict__ off,
                                                  int* __restrict__ fpos_rep){
  int i = blockIdx.x*256 + threadIdx.x;
  if (i < NN){
    int p = off[i];
    #pragma unroll
    for (int r=0; r<RREP; ++r){
      fpos_rep[r*RSTRIDE + i] = p;
      p += cnt_rep[r*RSTRIDE + i];
    }
  }
}

__global__ __launch_bounds__(256) void k_fill_rep(const int* __restrict__ src,
                                                  const int* __restrict__ dst,
                                                  int* __restrict__ fpos_rep,
                                                  int* __restrict__ csr, int n){
  int i = blockIdx.x*256 + threadIdx.x;
  int r = blockIdx.x & (RREP-1);
  if (i < n){
    int p = atomicAdd(&fpos_rep[r*RSTRIDE + dst[i]], 1);
    csr[p] = src[i];
  }
}

// ---------------- weight pre-transpose to bf16 ----------------
// Wt layout per layer: [256 rows][64 k] bf16; rows 0..63=q cols, 64..127=k, 128..191=v, 192..255=o
__global__ __launch_bounds__(256) void k_wt(const float* __restrict__ Wq,
                                            const float* __restrict__ Wk,
                                            const float* __restrict__ Wv,
                                            const float* __restrict__ Wo,
                                            unsigned short* __restrict__ Wt){
  int gid = blockIdx.x*256 + threadIdx.x;   // 49152 total
  int l   = gid >> 14;
  int rem = gid & 16383;
  int mat = rem >> 12;
  int idx = rem & 4095;
  int c = idx >> 6, n = idx & 63;
  const float* srcp = (mat==0)?Wq:(mat==1)?Wk:(mat==2)?Wv:Wo;
  float v = srcp[l*4096 + idx];
  Wt[l*16384 + (mat*64 + n)*64 + c] = f2bf(v);
}

// ---------------- elementwise fp32 -> bf16 ----------------
__global__ __launch_bounds__(256) void k_f2bf(const float* __restrict__ in,
                                              unsigned short* __restrict__ out){
  int i = blockIdx.x*256 + threadIdx.x;   // one ushort4 per thread
  float4 v = ((const float4*)in)[i];
  ushort4 o; o.x=f2bf(v.x); o.y=f2bf(v.y); o.z=f2bf(v.z); o.w=f2bf(v.w);
  ((ushort4*)out)[i] = o;
}

// ---------------- GIN aggregate via CSR gather (bf16 table, fp32 accum) ----------------
__global__ __launch_bounds__(256) void k_aggregate(const unsigned short* __restrict__ pre,
                                                   const int* __restrict__ off,
                                                   const int* __restrict__ csr,
                                                   float* __restrict__ agg){
  int w = threadIdx.x >> 6, lane = threadIdx.x & 63;
  int node = blockIdx.x*4 + w;
  int s = off[node], e = off[node+1];
  const ushort4* base = (const ushort4*)pre;
  ushort4 u = base[node*64 + lane];
  float a0 = bf2f(u.x), a1 = bf2f(u.y), a2 = bf2f(u.z), a3 = bf2f(u.w);
  int i = s;
  for (; i + 4 <= e; i += 4){
    int n0 = csr[i], n1 = csr[i+1], n2 = csr[i+2], n3 = csr[i+3];
    ushort4 u0 = base[n0*64 + lane], u1 = base[n1*64 + lane];
    ushort4 u2 = base[n2*64 + lane], u3 = base[n3*64 + lane];
    a0 += bf2f(u0.x)+bf2f(u1.x)+bf2f(u2.x)+bf2f(u3.x);
    a1 += bf2f(u0.y)+bf2f(u1.y)+bf2f(u2.y)+bf2f(u3.y);
    a2 += bf2f(u0.z)+bf2f(u1.z)+bf2f(u2.z)+bf2f(u3.z);
    a3 += bf2f(u0.w)+bf2f(u1.w)+bf2f(u2.w)+bf2f(u3.w);
  }
  for (; i < e; ++i){
    int n0 = csr[i];
    ushort4 u0 = base[n0*64 + lane];
    a0 += bf2f(u0.x); a1 += bf2f(u0.y); a2 += bf2f(u0.z); a3 += bf2f(u0.w);
  }
  ((float4*)agg)[node*64 + lane] = make_float4(a0, a1, a2, a3);
}

// ---------------- fused SAB: LN -> QKV (MFMA) -> attn(S=4) -> O-proj (MFMA) -> residual
//                  -> epilogue: write h, relu+LN2 -> lnout (into agg), LN1 -> bf16 pre_next
// one wave = 4 nodes = 16 rows; block = 4 waves = 16 nodes; grid = 3125. Wave-private LDS, no __syncthreads.
__global__ __launch_bounds__(256) void k_sab(float* __restrict__ agg,
                                             float* __restrict__ h,
                                             unsigned short* __restrict__ pre_next,
                                             const unsigned short* __restrict__ Wt,
                                             const float* __restrict__ lng,
                                             const float* __restrict__ lnb,
                                             const float* __restrict__ g2,
                                             const float* __restrict__ b2,
                                             const float* __restrict__ g1,
                                             const float* __restrict__ b1,
                                             int residual, int write_pre){
  __shared__ unsigned short xo_s[4][16][72];    // xin (phase1/2) then o (phase3/4), aliased
  __shared__ unsigned short qkv_s[4][16][200];  // cols 0..63 q, 64..127 k, 128..191 v

  int tid = threadIdx.x;
  int w = tid >> 6, lane = tid & 63;
  int c16 = lane & 15, kb = lane >> 4;
  int R0 = blockIdx.x*64 + w*16;   // 16 contiguous global rows (4 nodes)

  // phase 1: LN of agg rows -> bf16 staging
  {
    float4 gv = ((const float4*)lng)[c16];
    float4 bv = ((const float4*)lnb)[c16];
    #pragma unroll
    for (int rr=0; rr<4; ++rr){
      int m = rr*4 + kb;
      float4 v = ((const float4*)agg)[(R0+m)*16 + c16];
      float s = v.x+v.y+v.z+v.w;
      float q = v.x*v.x+v.y*v.y+v.z*v.z+v.w*v.w;
      #pragma unroll
      for (int d=1; d<16; d<<=1){ s += __shfl_xor(s, d); q += __shfl_xor(q, d); }
      float mu = s*(1.f/64.f);
      float rs = rsqrtf(q*(1.f/64.f) - mu*mu + 1e-5f);
      ushort4 o;
      o.x=f2bf((v.x-mu)*rs*gv.x+bv.x); o.y=f2bf((v.y-mu)*rs*gv.y+bv.y);
      o.z=f2bf((v.z-mu)*rs*gv.z+bv.z); o.w=f2bf((v.w-mu)*rs*gv.w+bv.w);
      *(ushort4*)&xo_s[w][m][c16*4] = o;
    }
  }

  // phase 2: QKV = xin @ Wqkv
  short8 a0 = *(const short8*)&xo_s[w][c16][kb*8];
  short8 a1 = *(const short8*)&xo_s[w][c16][32 + kb*8];
  f32x4 acc[12];
  #pragma unroll
  for (int t=0; t<12; ++t){
    short8 b0 = *(const short8*)&Wt[(t*16 + c16)*64 + kb*8];
    short8 b1 = *(const short8*)&Wt[(t*16 + c16)*64 + 32 + kb*8];
    f32x4 z = {0.f, 0.f, 0.f, 0.f};
    z = __builtin_amdgcn_mfma_f32_16x16x32_bf16(a0, b0, z, 0, 0, 0);
    z = __builtin_amdgcn_mfma_f32_16x16x32_bf16(a1, b1, z, 0, 0, 0);
    acc[t] = z;
  }
  // C/D layout: col=lane&15, row=(lane>>4)*4+reg
  #pragma unroll
  for (int t=0; t<12; ++t){
    #pragma unroll
    for (int r=0; r<4; ++r)
      qkv_s[w][kb*4 + r][t*16 + c16] = f2bf(acc[t][r]);
  }

  // phase 3: attention, S=4, per (node, head, q-row) lane
  {
    int p = lane >> 2, qr = lane & 3;
    int ns = p >> 2, hd = p & 3;
    int mrow = ns*4 + qr;
    int qc = hd*16, kc = 64 + hd*16, vc = 128 + hd*16;
    float qv[16];
    short8 u0 = *(const short8*)&qkv_s[w][mrow][qc];
    short8 u1 = *(const short8*)&qkv_s[w][mrow][qc+8];
    #pragma unroll
    for (int j=0; j<8; ++j){
      qv[j]   = bf2f((unsigned short)u0[j]);
      qv[8+j] = bf2f((unsigned short)u1[j]);
    }
    float sc[4];
    #pragma unroll
    for (int kr=0; kr<4; ++kr){
      short8 k0 = *(const short8*)&qkv_s[w][ns*4+kr][kc];
      short8 k1 = *(const short8*)&qkv_s[w][ns*4+kr][kc+8];
      float d2 = 0.f;
      #pragma unroll
      for (int j=0; j<8; ++j){
        d2 += qv[j]  *bf2f((unsigned short)k0[j]);
        d2 += qv[8+j]*bf2f((unsigned short)k1[j]);
      }
      sc[kr] = d2 * 0.25f;   // 1/sqrt(16)
    }
    float mx = fmaxf(fmaxf(sc[0],sc[1]), fmaxf(sc[2],sc[3]));
    float e0=__expf(sc[0]-mx), e1=__expf(sc[1]-mx), e2=__expf(sc[2]-mx), e3=__expf(sc[3]-mx);
    float inv = 1.f/(e0+e1+e2+e3);
    float at[4] = {e0*inv, e1*inv, e2*inv, e3*inv};
    float ov[16];
    #pragma unroll
    for (int j=0; j<16; ++j) ov[j] = 0.f;
    #pragma unroll
    for (int kr=0; kr<4; ++kr){
      short8 v0 = *(const short8*)&qkv_s[w][ns*4+kr][vc];
      short8 v1 = *(const short8*)&qkv_s[w][ns*4+kr][vc+8];
      #pragma unroll
      for (int j=0; j<8; ++j){
        ov[j]   += at[kr]*bf2f((unsigned short)v0[j]);
        ov[8+j] += at[kr]*bf2f((unsigned short)v1[j]);
      }
    }
    short8 s0v, s1v;
    #pragma unroll
    for (int j=0; j<8; ++j){
      s0v[j] = (short)f2bf(ov[j]);
      s1v[j] = (short)f2bf(ov[8+j]);
    }
    *(short8*)&xo_s[w][mrow][qc]   = s0v;
    *(short8*)&xo_s[w][mrow][qc+8] = s1v;
  }

  // phase 4: val = o @ Wo (+ h + agg if residual)
  short8 oa0 = *(const short8*)&xo_s[w][c16][kb*8];
  short8 oa1 = *(const short8*)&xo_s[w][c16][32 + kb*8];
  float val[4][4];   // [t][r]: row kb*4+r, col t*16+c16
  #pragma unroll
  for (int t=0; t<4; ++t){
    short8 b0 = *(const short8*)&Wt[(192 + t*16 + c16)*64 + kb*8];
    short8 b1 = *(const short8*)&Wt[(192 + t*16 + c16)*64 + 32 + kb*8];
    f32x4 z = {0.f, 0.f, 0.f, 0.f};
    z = __builtin_amdgcn_mfma_f32_16x16x32_bf16(oa0, b0, z, 0, 0, 0);
    z = __builtin_amdgcn_mfma_f32_16x16x32_bf16(oa1, b1, z, 0, 0, 0);
    #pragma unroll
    for (int r=0; r<4; ++r){
      float v = z[r];
      if (residual){
        int gi = (R0 + kb*4 + r)*64 + t*16 + c16;
        v += h[gi] + agg[gi];
      }
      val[t][r] = v;
    }
  }

  // epilogue: per-row stats for LN1 (raw) and LN2 (relu), 16-lane reductions
  float s1[4], q1[4], s2[4], q2[4];
  #pragma unroll
  for (int r=0; r<4; ++r){
    float a=0.f, b=0.f, c=0.f, d=0.f;
    #pragma unroll
    for (int t=0; t<4; ++t){
      float v = val[t][r];
      float rv = fmaxf(v, 0.f);
      a += v; b += v*v; c += rv; d += rv*rv;
    }
    s1[r]=a; q1[r]=b; s2[r]=c; q2[r]=d;
  }
  #pragma unroll
  for (int d=1; d<16; d<<=1){
    #pragma unroll
    for (int r=0; r<4; ++r){
      s1[r] += __shfl_xor(s1[r], d); q1[r] += __shfl_xor(q1[r], d);
      s2[r] += __shfl_xor(s2[r], d); q2[r] += __shfl_xor(q2[r], d);
    }
  }
  float mu1[4], rs1[4], mu2[4], rs2[4];
  #pragma unroll
  for (int r=0; r<4; ++r){
    mu1[r] = s1[r]*(1.f/64.f);
    rs1[r] = rsqrtf(q1[r]*(1.f/64.f) - mu1[r]*mu1[r] + 1e-5f);
    mu2[r] = s2[r]*(1.f/64.f);
    rs2[r] = rsqrtf(q2[r]*(1.f/64.f) - mu2[r]*mu2[r] + 1e-5f);
  }
  #pragma unroll
  for (int t=0; t<4; ++t){
    int col = t*16 + c16;
    float g2v = g2[col], b2v = b2[col];
    float g1v = 0.f, b1v = 0.f;
    if (write_pre){ g1v = g1[col]; b1v = b1[col]; }
    #pragma unroll
    for (int r=0; r<4; ++r){
      int gi = (R0 + kb*4 + r)*64 + col;
      float v = val[t][r];
      h[gi] = v;
      float rv = fmaxf(v, 0.f);
      agg[gi] = (rv - mu2[r])*rs2[r]*g2v + b2v;   // lnout for pooling (overwrites agg)
      if (write_pre)
        pre_next[gi] = f2bf((v - mu1[r])*rs1[r]*g1v + b1v);
    }
  }
}

// ---------------- per-graph pooling: 8 sub-blocks per graph, atomic merge ----------------
__global__ __launch_bounds__(256) void k_pool8(const float* __restrict__ src,
                                               const int* __restrict__ goff,
                                               float* __restrict__ out){
  int g = blockIdx.x >> 3, sub = blockIdx.x & 7, t = threadIdx.x;
  int s = goff[g], e = goff[g+1], len = e - s;
  int s0 = s + ((len*sub) >> 3), e0 = s + ((len*(sub+1)) >> 3);
  float a0=0.f, a1=0.f;
  int n = s0;
  for (; n + 2 <= e0; n += 2){ a0 += src[n*256 + t]; a1 += src[(n+1)*256 + t]; }
  if (n < e0) a0 += src[n*256 + t];
  atomicAdd(&out[g*256 + t], a0 + a1);
}

// ---------------- final: score = sum_i pooled_i @ W_pred[i] + b_pred[i] ----------------
__global__ __launch_bounds__(256) void k_final(const float* __restrict__ pooled,
                                               const float* __restrict__ Wp,
                                               const float* __restrict__ bp,
                                               float* __restrict__ out){
  int t = blockIdx.x*256 + threadIdx.x;  // 8192 = 128*4*16
  int b = t >> 6, s = (t >> 4) & 3, o = t & 15;
  float acc = 0.f;
  for (int i=0; i<4; ++i){
    acc += bp[i*16 + o];
    const float* pr = pooled + i*32768 + b*256 + s*64;
    const float* wp = Wp + i*1024 + o;
    float a = 0.f;
    #pragma unroll 8
    for (int c=0; c<64; ++c) a += pr[c]*wp[c*16];
    acc += a;
  }
  out[t] = acc;
}

// ---------------- workspace layout (bytes) ----------------
static const size_t OFF_H    = 0;           // fp32 [50000*256]; cnt_rep/fpos_rep alias here during build
static const size_t OFF_AGG  = 51200000;    // fp32 [50000*256] (becomes lnout after SAB)
static const size_t OFF_PRE  = 102400000;   // bf16 [50000*256]
static const size_t OFF_CSR  = 128000000;   // int [800000]
static const size_t OFF_CNT  = 131200000;   // int [50000]
static const size_t OFF_OFF  = 131400064;   // int [50001]
static const size_t OFF_GCNT = 131800192;   // int [128]
static const size_t OFF_GOFF = 131800768;   // int [129]
static const size_t OFF_GFIL = 131801344;   // int [128]
static const size_t OFF_POOL = 131801920;   // fp32 [4][128*256]
static const size_t OFF_WT   = 132326208;   // bf16 [3][256*64]
static const size_t OFF_BSUM = 132424576;   // int [196]
static const size_t OFF_BOFF = 132425472;   // int [197]

extern "C" void kernel_launch(void* const* d_in, const int* in_sizes, int n_in,
                              void* d_out, int out_size, void* d_ws, size_t ws_size,
                              hipStream_t stream) {
  const float* feat = (const float*)d_in[0];
  const int*   src  = (const int*)d_in[1];
  const int*   dst  = (const int*)d_in[2];
  const int*   gid  = (const int*)d_in[3];
  const float* Wq   = (const float*)d_in[4];
  const float* Wk   = (const float*)d_in[5];
  const float* Wv   = (const float*)d_in[6];
  const float* Wo   = (const float*)d_in[7];
  const float* sg   = (const float*)d_in[8];
  const float* sb   = (const float*)d_in[9];
  const float* l1g  = (const float*)d_in[10];
  const float* l1b  = (const float*)d_in[11];
  const float* l2g  = (const float*)d_in[12];
  const float* l2b  = (const float*)d_in[13];
  const float* Wp   = (const float*)d_in[14];
  const float* bp   = (const float*)d_in[15];
  float* out = (float*)d_out;

  char* ws = (char*)d_ws;
  float*          h      = (float*)(ws + OFF_H);
  float*          agg    = (float*)(ws + OFF_AGG);
  unsigned short* pre    = (unsigned short*)(ws + OFF_PRE);
  int*            csr    = (int*)(ws + OFF_CSR);
  int*            cnt    = (int*)(ws + OFF_CNT);
  int*            off    = (int*)(ws + OFF_OFF);
  int*            gcnt   = (int*)(ws + OFF_GCNT);
  int*            goff   = (int*)(ws + OFF_GOFF);
  int*            gfil   = (int*)(ws + OFF_GFIL);
  float*          pooled = (float*)(ws + OFF_POOL);
  unsigned short* Wt     = (unsigned short*)(ws + OFF_WT);
  int*            bsum   = (int*)(ws + OFF_BSUM);
  int*            boff   = (int*)(ws + OFF_BOFF);
  // replicated build scratch aliases the h region (h is first written by k_sab, after build)
  int*            cnt_rep  = (int*)(ws + OFF_H);
  int*            fpos_rep = (int*)(ws + OFF_H + (size_t)RREP*RSTRIDE*4);

  hipMemsetAsync(cnt_rep, 0, (size_t)RREP*RSTRIDE*4, stream);
  hipMemsetAsync(gcnt, 0, NG*sizeof(int), stream);
  hipMemsetAsync(pooled, 0, 4*NG*256*sizeof(float), stream);

  // CSR for dst (replicated); graph offsets (graph_ids sorted)
  k_count_rep<<<NE/256, 256, 0, stream>>>(dst, cnt_rep, NE);
  k_count<<<(NN+255)/256, 256, 0, stream>>>(gid, gcnt, NN);
  k_reduce_rep<<<(NN+255)/256, 256, 0, stream>>>(cnt_rep, cnt);
  k_blocksum<<<196, 256, 0, stream>>>(cnt, NN, bsum);
  k_scan_small<<<1, 256, 0, stream>>>(bsum, 196, boff, (int*)0);
  k_scan_small<<<1, 256, 0, stream>>>(gcnt, NG, goff, gfil);
  k_scan_apply<<<196, 256, 0, stream>>>(cnt, NN, boff, off);
  k_fpos_rep<<<(NN+255)/256, 256, 0, stream>>>(cnt_rep, off, fpos_rep);
  k_fill_rep<<<NE/256, 256, 0, stream>>>(src, dst, fpos_rep, csr, NE);

  // weights transpose + feat->bf16 + hidden_rep[0] pooling
  k_wt<<<192, 256, 0, stream>>>(Wq, Wk, Wv, Wo, Wt);
  k_f2bf<<<12500, 256, 0, stream>>>(feat, pre);
  k_pool8<<<NG*8, 256, 0, stream>>>(feat, goff, pooled + 0*32768);

  // layer 0: agg = feat + segsum(feat[src]); h = SAB(agg); fused relu+LN2 -> agg, LN1(i=1) -> pre
  k_aggregate<<<12500, 256, 0, stream>>>(pre, off, csr, agg);
  k_sab<<<3125, 256, 0, stream>>>(agg, h, pre, Wt + 0*16384,
                                  sg + 0, sb + 0, l2g + 0, l2b + 0,
                                  l1g + 1*64, l1b + 1*64, 0, 1);
  k_pool8<<<NG*8, 256, 0, stream>>>(agg, goff, pooled + 1*32768);

  // layers 1,2
  for (int i = 1; i < 3; ++i){
    k_aggregate<<<12500, 256, 0, stream>>>(pre, off, csr, agg);
    int wp = (i < 2) ? 1 : 0;
    k_sab<<<3125, 256, 0, stream>>>(agg, h, pre, Wt + i*16384,
                                    sg + i*64, sb + i*64, l2g + i*64, l2b + i*64,
                                    l1g + (i+1)*64, l1b + (i+1)*64, 1, wp);
    k_pool8<<<NG*8, 256, 0, stream>>>(agg, goff, pooled + (i+1)*32768);
  }

  k_final<<<32, 256, 0, stream>>>(pooled, Wp, bp, out);
}

// Round 3
// 698.871 us; speedup vs baseline: 1.3094x; 1.1693x over previous
//
#include <hip/hip_runtime.h>

#define NN 50000
#define NE 800000
#define NG 128
#define RREP 16
#define RSTRIDE 50048

typedef __attribute__((ext_vector_type(8))) short short8;
typedef __attribute__((ext_vector_type(4))) float f32x4;

__device__ __forceinline__ unsigned short f2bf(float f){
  union { float f; unsigned int u; } v; v.f = f;
  return (unsigned short)((v.u + 0x7fffu + ((v.u >> 16) & 1u)) >> 16);
}
__device__ __forceinline__ float bf2f(unsigned short h){
  union { unsigned int u; float f; } v; v.u = ((unsigned int)h) << 16;
  return v.f;
}

// ---------------- graph offsets from SORTED graph_ids: boundary scan, zero atomics ----------------
__global__ __launch_bounds__(256) void k_goff(const int* __restrict__ gid,
                                              int* __restrict__ goff){
  int i = blockIdx.x*256 + threadIdx.x;
  if (i >= NN) return;
  int c = gid[i];
  int p = (i == 0) ? -1 : gid[i-1];
  for (int g = p+1; g <= c; ++g) goff[g] = i;
  if (i == NN-1){
    for (int g = c+1; g <= NG; ++g) goff[g] = NN;
  }
}

// ---------------- CSR build (16-way replicated histograms to kill atomic line contention) ----------------
__global__ __launch_bounds__(256) void k_count_rep(const int* __restrict__ idx,
                                                   int* __restrict__ cnt_rep, int n){
  int i = blockIdx.x*256 + threadIdx.x;
  int r = blockIdx.x & (RREP-1);
  if (i < n) atomicAdd(&cnt_rep[r*RSTRIDE + idx[i]], 1);
}

__global__ __launch_bounds__(256) void k_reduce_rep(const int* __restrict__ cnt_rep,
                                                    int* __restrict__ cnt){
  int i = blockIdx.x*256 + threadIdx.x;
  if (i < NN){
    int s = 0;
    #pragma unroll
    for (int r=0; r<RREP; ++r) s += cnt_rep[r*RSTRIDE + i];
    cnt[i] = s;
  }
}

__global__ __launch_bounds__(256) void k_blocksum(const int* __restrict__ in, int n,
                                                  int* __restrict__ bsum){
  __shared__ int ws4[4];
  int i = blockIdx.x*256 + threadIdx.x;
  int v = (i < n) ? in[i] : 0;
  #pragma unroll
  for (int d=1; d<64; d<<=1) v += __shfl_xor(v, d);
  int lane = threadIdx.x & 63, w = threadIdx.x >> 6;
  if (lane == 0) ws4[w] = v;
  __syncthreads();
  if (threadIdx.x == 0) bsum[blockIdx.x] = ws4[0]+ws4[1]+ws4[2]+ws4[3];
}

// exclusive scan of n<=256 elements, single block of 256; out[n]=total
__global__ __launch_bounds__(256) void k_scan_small(const int* __restrict__ in, int n,
                                                    int* __restrict__ out){
  __shared__ int wsum[4];
  int tid = threadIdx.x, lane = tid & 63, w = tid >> 6;
  int v = (tid < n) ? in[tid] : 0;
  int x = v;
  #pragma unroll
  for (int d=1; d<64; d<<=1){ int y = __shfl_up(x, d); if (lane >= d) x += y; }
  if (lane == 63) wsum[w] = x;
  __syncthreads();
  int pre2 = 0;
  for (int j=0; j<w; ++j) pre2 += wsum[j];
  int incl = x + pre2;
  if (tid < n) out[tid] = incl - v;
  if (tid == n-1) out[n] = incl;
}

__global__ __launch_bounds__(256) void k_scan_apply(const int* __restrict__ in, int n,
                                                    const int* __restrict__ boff,
                                                    int* __restrict__ out){
  __shared__ int wsum[4];
  int tid = threadIdx.x, lane = tid & 63, w = tid >> 6;
  int i = blockIdx.x*256 + tid;
  int v = (i < n) ? in[i] : 0;
  int x = v;
  #pragma unroll
  for (int d=1; d<64; d<<=1){ int y = __shfl_up(x, d); if (lane >= d) x += y; }
  if (lane == 63) wsum[w] = x;
  __syncthreads();
  int pre2 = boff[blockIdx.x];
  for (int j=0; j<w; ++j) pre2 += wsum[j];
  int excl = x - v + pre2;
  if (i < n){
    out[i] = excl;
    if (i == n-1) out[n] = excl + v;
  }
}

// per-replica fill cursors: fpos_rep[r][n] = off[n] + sum_{j<r} cnt_rep[j][n]
__global__ __launch_bounds__(256) void k_fpos_rep(const int* __restrict__ cnt_rep,
                                                  const int* __restrict__ off,
                                                  int* __restrict__ fpos_rep){
  int i = blockIdx.x*256 + threadIdx.x;
  if (i < NN){
    int p = off[i];
    #pragma unroll
    for (int r=0; r<RREP; ++r){
      fpos_rep[r*RSTRIDE + i] = p;
      p += cnt_rep[r*RSTRIDE + i];
    }
  }
}

__global__ __launch_bounds__(256) void k_fill_rep(const int* __restrict__ src,
                                                  const int* __restrict__ dst,
                                                  int* __restrict__ fpos_rep,
                                                  int* __restrict__ csr, int n){
  int i = blockIdx.x*256 + threadIdx.x;
  int r = blockIdx.x & (RREP-1);
  if (i < n){
    int p = atomicAdd(&fpos_rep[r*RSTRIDE + dst[i]], 1);
    csr[p] = src[i];
  }
}

// ---------------- weight pre-transpose to bf16 ----------------
// Wt layout per layer: [256 rows][64 k] bf16; rows 0..63=q cols, 64..127=k, 128..191=v, 192..255=o
__global__ __launch_bounds__(256) void k_wt(const float* __restrict__ Wq,
                                            const float* __restrict__ Wk,
                                            const float* __restrict__ Wv,
                                            const float* __restrict__ Wo,
                                            unsigned short* __restrict__ Wt){
  int gid = blockIdx.x*256 + threadIdx.x;   // 49152 total
  int l   = gid >> 14;
  int rem = gid & 16383;
  int mat = rem >> 12;
  int idx = rem & 4095;
  int c = idx >> 6, n = idx & 63;
  const float* srcp = (mat==0)?Wq:(mat==1)?Wk:(mat==2)?Wv:Wo;
  float v = srcp[l*4096 + idx];
  Wt[l*16384 + (mat*64 + n)*64 + c] = f2bf(v);
}

// ---------------- elementwise fp32 -> bf16 ----------------
__global__ __launch_bounds__(256) void k_f2bf(const float* __restrict__ in,
                                              unsigned short* __restrict__ out){
  int i = blockIdx.x*256 + threadIdx.x;   // one ushort4 per thread
  float4 v = ((const float4*)in)[i];
  ushort4 o; o.x=f2bf(v.x); o.y=f2bf(v.y); o.z=f2bf(v.z); o.w=f2bf(v.w);
  ((ushort4*)out)[i] = o;
}

// ---------------- GIN aggregate via CSR gather (bf16 table, fp32 accum) ----------------
__global__ __launch_bounds__(256) void k_aggregate(const unsigned short* __restrict__ pre,
                                                   const int* __restrict__ off,
                                                   const int* __restrict__ csr,
                                                   float* __restrict__ agg){
  int w = threadIdx.x >> 6, lane = threadIdx.x & 63;
  int node = blockIdx.x*4 + w;
  int s = off[node], e = off[node+1];
  const ushort4* base = (const ushort4*)pre;
  ushort4 u = base[node*64 + lane];
  float a0 = bf2f(u.x), a1 = bf2f(u.y), a2 = bf2f(u.z), a3 = bf2f(u.w);
  int i = s;
  for (; i + 4 <= e; i += 4){
    int n0 = csr[i], n1 = csr[i+1], n2 = csr[i+2], n3 = csr[i+3];
    ushort4 u0 = base[n0*64 + lane], u1 = base[n1*64 + lane];
    ushort4 u2 = base[n2*64 + lane], u3 = base[n3*64 + lane];
    a0 += bf2f(u0.x)+bf2f(u1.x)+bf2f(u2.x)+bf2f(u3.x);
    a1 += bf2f(u0.y)+bf2f(u1.y)+bf2f(u2.y)+bf2f(u3.y);
    a2 += bf2f(u0.z)+bf2f(u1.z)+bf2f(u2.z)+bf2f(u3.z);
    a3 += bf2f(u0.w)+bf2f(u1.w)+bf2f(u2.w)+bf2f(u3.w);
  }
  for (; i < e; ++i){
    int n0 = csr[i];
    ushort4 u0 = base[n0*64 + lane];
    a0 += bf2f(u0.x); a1 += bf2f(u0.y); a2 += bf2f(u0.z); a3 += bf2f(u0.w);
  }
  ((float4*)agg)[node*64 + lane] = make_float4(a0, a1, a2, a3);
}

// ---------------- fused SAB: LN -> QKV (MFMA) -> attn(S=4) -> O-proj (MFMA) -> residual
//                  -> epilogue: write h, relu+LN2 -> lnout (into agg), LN1 -> bf16 pre_next
// one wave = 4 nodes = 16 rows; block = 4 waves = 16 nodes; grid = 3125. Wave-private LDS, no __syncthreads.
__global__ __launch_bounds__(256) void k_sab(float* __restrict__ agg,
                                             float* __restrict__ h,
                                             unsigned short* __restrict__ pre_next,
                                             const unsigned short* __restrict__ Wt,
                                             const float* __restrict__ lng,
                                             const float* __restrict__ lnb,
                                             const float* __restrict__ g2,
                                             const float* __restrict__ b2,
                                             const float* __restrict__ g1,
                                             const float* __restrict__ b1,
                                             int residual, int write_pre){
  __shared__ unsigned short xo_s[4][16][72];    // xin (phase1/2) then o (phase3/4), aliased
  __shared__ unsigned short qkv_s[4][16][200];  // cols 0..63 q, 64..127 k, 128..191 v

  int tid = threadIdx.x;
  int w = tid >> 6, lane = tid & 63;
  int c16 = lane & 15, kb = lane >> 4;
  int R0 = blockIdx.x*64 + w*16;   // 16 contiguous global rows (4 nodes)

  // phase 1: LN of agg rows -> bf16 staging
  {
    float4 gv = ((const float4*)lng)[c16];
    float4 bv = ((const float4*)lnb)[c16];
    #pragma unroll
    for (int rr=0; rr<4; ++rr){
      int m = rr*4 + kb;
      float4 v = ((const float4*)agg)[(R0+m)*16 + c16];
      float s = v.x+v.y+v.z+v.w;
      float q = v.x*v.x+v.y*v.y+v.z*v.z+v.w*v.w;
      #pragma unroll
      for (int d=1; d<16; d<<=1){ s += __shfl_xor(s, d); q += __shfl_xor(q, d); }
      float mu = s*(1.f/64.f);
      float rs = rsqrtf(q*(1.f/64.f) - mu*mu + 1e-5f);
      ushort4 o;
      o.x=f2bf((v.x-mu)*rs*gv.x+bv.x); o.y=f2bf((v.y-mu)*rs*gv.y+bv.y);
      o.z=f2bf((v.z-mu)*rs*gv.z+bv.z); o.w=f2bf((v.w-mu)*rs*gv.w+bv.w);
      *(ushort4*)&xo_s[w][m][c16*4] = o;
    }
  }

  // phase 2: QKV = xin @ Wqkv
  short8 a0 = *(const short8*)&xo_s[w][c16][kb*8];
  short8 a1 = *(const short8*)&xo_s[w][c16][32 + kb*8];
  f32x4 acc[12];
  #pragma unroll
  for (int t=0; t<12; ++t){
    short8 b0 = *(const short8*)&Wt[(t*16 + c16)*64 + kb*8];
    short8 b1 = *(const short8*)&Wt[(t*16 + c16)*64 + 32 + kb*8];
    f32x4 z = {0.f, 0.f, 0.f, 0.f};
    z = __builtin_amdgcn_mfma_f32_16x16x32_bf16(a0, b0, z, 0, 0, 0);
    z = __builtin_amdgcn_mfma_f32_16x16x32_bf16(a1, b1, z, 0, 0, 0);
    acc[t] = z;
  }
  // C/D layout: col=lane&15, row=(lane>>4)*4+reg
  #pragma unroll
  for (int t=0; t<12; ++t){
    #pragma unroll
    for (int r=0; r<4; ++r)
      qkv_s[w][kb*4 + r][t*16 + c16] = f2bf(acc[t][r]);
  }

  // phase 3: attention, S=4, per (node, head, q-row) lane
  {
    int p = lane >> 2, qr = lane & 3;
    int ns = p >> 2, hd = p & 3;
    int mrow = ns*4 + qr;
    int qc = hd*16, kc = 64 + hd*16, vc = 128 + hd*16;
    float qv[16];
    short8 u0 = *(const short8*)&qkv_s[w][mrow][qc];
    short8 u1 = *(const short8*)&qkv_s[w][mrow][qc+8];
    #pragma unroll
    for (int j=0; j<8; ++j){
      qv[j]   = bf2f((unsigned short)u0[j]);
      qv[8+j] = bf2f((unsigned short)u1[j]);
    }
    float sc[4];
    #pragma unroll
    for (int kr=0; kr<4; ++kr){
      short8 k0 = *(const short8*)&qkv_s[w][ns*4+kr][kc];
      short8 k1 = *(const short8*)&qkv_s[w][ns*4+kr][kc+8];
      float d2 = 0.f;
      #pragma unroll
      for (int j=0; j<8; ++j){
        d2 += qv[j]  *bf2f((unsigned short)k0[j]);
        d2 += qv[8+j]*bf2f((unsigned short)k1[j]);
      }
      sc[kr] = d2 * 0.25f;   // 1/sqrt(16)
    }
    float mx = fmaxf(fmaxf(sc[0],sc[1]), fmaxf(sc[2],sc[3]));
    float e0=__expf(sc[0]-mx), e1=__expf(sc[1]-mx), e2=__expf(sc[2]-mx), e3=__expf(sc[3]-mx);
    float inv = 1.f/(e0+e1+e2+e3);
    float at[4] = {e0*inv, e1*inv, e2*inv, e3*inv};
    float ov[16];
    #pragma unroll
    for (int j=0; j<16; ++j) ov[j] = 0.f;
    #pragma unroll
    for (int kr=0; kr<4; ++kr){
      short8 v0 = *(const short8*)&qkv_s[w][ns*4+kr][vc];
      short8 v1 = *(const short8*)&qkv_s[w][ns*4+kr][vc+8];
      #pragma unroll
      for (int j=0; j<8; ++j){
        ov[j]   += at[kr]*bf2f((unsigned short)v0[j]);
        ov[8+j] += at[kr]*bf2f((unsigned short)v1[j]);
      }
    }
    short8 s0v, s1v;
    #pragma unroll
    for (int j=0; j<8; ++j){
      s0v[j] = (short)f2bf(ov[j]);
      s1v[j] = (short)f2bf(ov[8+j]);
    }
    *(short8*)&xo_s[w][mrow][qc]   = s0v;
    *(short8*)&xo_s[w][mrow][qc+8] = s1v;
  }

  // phase 4: val = o @ Wo (+ h + agg if residual)
  short8 oa0 = *(const short8*)&xo_s[w][c16][kb*8];
  short8 oa1 = *(const short8*)&xo_s[w][c16][32 + kb*8];
  float val[4][4];   // [t][r]: row kb*4+r, col t*16+c16
  #pragma unroll
  for (int t=0; t<4; ++t){
    short8 b0 = *(const short8*)&Wt[(192 + t*16 + c16)*64 + kb*8];
    short8 b1 = *(const short8*)&Wt[(192 + t*16 + c16)*64 + 32 + kb*8];
    f32x4 z = {0.f, 0.f, 0.f, 0.f};
    z = __builtin_amdgcn_mfma_f32_16x16x32_bf16(oa0, b0, z, 0, 0, 0);
    z = __builtin_amdgcn_mfma_f32_16x16x32_bf16(oa1, b1, z, 0, 0, 0);
    #pragma unroll
    for (int r=0; r<4; ++r){
      float v = z[r];
      if (residual){
        int gi = (R0 + kb*4 + r)*64 + t*16 + c16;
        v += h[gi] + agg[gi];
      }
      val[t][r] = v;
    }
  }

  // epilogue: per-row stats for LN1 (raw) and LN2 (relu), 16-lane reductions
  float s1[4], q1[4], s2[4], q2[4];
  #pragma unroll
  for (int r=0; r<4; ++r){
    float a=0.f, b=0.f, c=0.f, d=0.f;
    #pragma unroll
    for (int t=0; t<4; ++t){
      float v = val[t][r];
      float rv = fmaxf(v, 0.f);
      a += v; b += v*v; c += rv; d += rv*rv;
    }
    s1[r]=a; q1[r]=b; s2[r]=c; q2[r]=d;
  }
  #pragma unroll
  for (int d=1; d<16; d<<=1){
    #pragma unroll
    for (int r=0; r<4; ++r){
      s1[r] += __shfl_xor(s1[r], d); q1[r] += __shfl_xor(q1[r], d);
      s2[r] += __shfl_xor(s2[r], d); q2[r] += __shfl_xor(q2[r], d);
    }
  }
  float mu1[4], rs1[4], mu2[4], rs2[4];
  #pragma unroll
  for (int r=0; r<4; ++r){
    mu1[r] = s1[r]*(1.f/64.f);
    rs1[r] = rsqrtf(q1[r]*(1.f/64.f) - mu1[r]*mu1[r] + 1e-5f);
    mu2[r] = s2[r]*(1.f/64.f);
    rs2[r] = rsqrtf(q2[r]*(1.f/64.f) - mu2[r]*mu2[r] + 1e-5f);
  }
  #pragma unroll
  for (int t=0; t<4; ++t){
    int col = t*16 + c16;
    float g2v = g2[col], b2v = b2[col];
    float g1v = 0.f, b1v = 0.f;
    if (write_pre){ g1v = g1[col]; b1v = b1[col]; }
    #pragma unroll
    for (int r=0; r<4; ++r){
      int gi = (R0 + kb*4 + r)*64 + col;
      float v = val[t][r];
      h[gi] = v;
      float rv = fmaxf(v, 0.f);
      agg[gi] = (rv - mu2[r])*rs2[r]*g2v + b2v;   // lnout for pooling (overwrites agg)
      if (write_pre)
        pre_next[gi] = f2bf((v - mu1[r])*rs1[r]*g1v + b1v);
    }
  }
}

// ---------------- per-graph pooling: 8 sub-blocks per graph, atomic merge ----------------
__global__ __launch_bounds__(256) void k_pool8(const float* __restrict__ src,
                                               const int* __restrict__ goff,
                                               float* __restrict__ out){
  int g = blockIdx.x >> 3, sub = blockIdx.x & 7, t = threadIdx.x;
  int s = goff[g], e = goff[g+1], len = e - s;
  int s0 = s + ((len*sub) >> 3), e0 = s + ((len*(sub+1)) >> 3);
  float a0=0.f, a1=0.f;
  int n = s0;
  for (; n + 2 <= e0; n += 2){ a0 += src[n*256 + t]; a1 += src[(n+1)*256 + t]; }
  if (n < e0) a0 += src[n*256 + t];
  atomicAdd(&out[g*256 + t], a0 + a1);
}

// ---------------- final: score = sum_i pooled_i @ W_pred[i] + b_pred[i] ----------------
__global__ __launch_bounds__(256) void k_final(const float* __restrict__ pooled,
                                               const float* __restrict__ Wp,
                                               const float* __restrict__ bp,
                                               float* __restrict__ out){
  int t = blockIdx.x*256 + threadIdx.x;  // 8192 = 128*4*16
  int b = t >> 6, s = (t >> 4) & 3, o = t & 15;
  float acc = 0.f;
  for (int i=0; i<4; ++i){
    acc += bp[i*16 + o];
    const float* pr = pooled + i*32768 + b*256 + s*64;
    const float* wp = Wp + i*1024 + o;
    float a = 0.f;
    #pragma unroll 8
    for (int c=0; c<64; ++c) a += pr[c]*wp[c*16];
    acc += a;
  }
  out[t] = acc;
}

// ---------------- workspace layout (bytes) ----------------
static const size_t OFF_H    = 0;           // fp32 [50000*256]; cnt_rep/fpos_rep alias here during build
static const size_t OFF_AGG  = 51200000;    // fp32 [50000*256] (becomes lnout after SAB)
static const size_t OFF_PRE  = 102400000;   // bf16 [50000*256]
static const size_t OFF_CSR  = 128000000;   // int [800000]
static const size_t OFF_CNT  = 131200000;   // int [50000]
static const size_t OFF_OFF  = 131400064;   // int [50001]
static const size_t OFF_GOFF = 131800768;   // int [129]
static const size_t OFF_POOL = 131801920;   // fp32 [4][128*256]
static const size_t OFF_WT   = 132326208;   // bf16 [3][256*64]
static const size_t OFF_BSUM = 132424576;   // int [196]
static const size_t OFF_BOFF = 132425472;   // int [197]

extern "C" void kernel_launch(void* const* d_in, const int* in_sizes, int n_in,
                              void* d_out, int out_size, void* d_ws, size_t ws_size,
                              hipStream_t stream) {
  const float* feat = (const float*)d_in[0];
  const int*   src  = (const int*)d_in[1];
  const int*   dst  = (const int*)d_in[2];
  const int*   gid  = (const int*)d_in[3];
  const float* Wq   = (const float*)d_in[4];
  const float* Wk   = (const float*)d_in[5];
  const float* Wv   = (const float*)d_in[6];
  const float* Wo   = (const float*)d_in[7];
  const float* sg   = (const float*)d_in[8];
  const float* sb   = (const float*)d_in[9];
  const float* l1g  = (const float*)d_in[10];
  const float* l1b  = (const float*)d_in[11];
  const float* l2g  = (const float*)d_in[12];
  const float* l2b  = (const float*)d_in[13];
  const float* Wp   = (const float*)d_in[14];
  const float* bp   = (const float*)d_in[15];
  float* out = (float*)d_out;

  char* ws = (char*)d_ws;
  float*          h      = (float*)(ws + OFF_H);
  float*          agg    = (float*)(ws + OFF_AGG);
  unsigned short* pre    = (unsigned short*)(ws + OFF_PRE);
  int*            csr    = (int*)(ws + OFF_CSR);
  int*            cnt    = (int*)(ws + OFF_CNT);
  int*            off    = (int*)(ws + OFF_OFF);
  int*            goff   = (int*)(ws + OFF_GOFF);
  float*          pooled = (float*)(ws + OFF_POOL);
  unsigned short* Wt     = (unsigned short*)(ws + OFF_WT);
  int*            bsum   = (int*)(ws + OFF_BSUM);
  int*            boff   = (int*)(ws + OFF_BOFF);
  // replicated build scratch aliases the h region (h is first written by k_sab, after build)
  int*            cnt_rep  = (int*)(ws + OFF_H);
  int*            fpos_rep = (int*)(ws + OFF_H + (size_t)RREP*RSTRIDE*4);

  hipMemsetAsync(cnt_rep, 0, (size_t)RREP*RSTRIDE*4, stream);
  hipMemsetAsync(pooled, 0, 4*NG*256*sizeof(float), stream);

  // CSR for dst (replicated histograms); graph offsets via sorted-boundary scan
  k_count_rep<<<NE/256, 256, 0, stream>>>(dst, cnt_rep, NE);
  k_goff<<<(NN+255)/256, 256, 0, stream>>>(gid, goff);
  k_reduce_rep<<<(NN+255)/256, 256, 0, stream>>>(cnt_rep, cnt);
  k_blocksum<<<196, 256, 0, stream>>>(cnt, NN, bsum);
  k_scan_small<<<1, 256, 0, stream>>>(bsum, 196, boff);
  k_scan_apply<<<196, 256, 0, stream>>>(cnt, NN, boff, off);
  k_fpos_rep<<<(NN+255)/256, 256, 0, stream>>>(cnt_rep, off, fpos_rep);
  k_fill_rep<<<NE/256, 256, 0, stream>>>(src, dst, fpos_rep, csr, NE);

  // weights transpose + feat->bf16 + hidden_rep[0] pooling
  k_wt<<<192, 256, 0, stream>>>(Wq, Wk, Wv, Wo, Wt);
  k_f2bf<<<12500, 256, 0, stream>>>(feat, pre);
  k_pool8<<<NG*8, 256, 0, stream>>>(feat, goff, pooled + 0*32768);

  // layer 0: agg = feat + segsum(feat[src]); h = SAB(agg); fused relu+LN2 -> agg, LN1(i=1) -> pre
  k_aggregate<<<12500, 256, 0, stream>>>(pre, off, csr, agg);
  k_sab<<<3125, 256, 0, stream>>>(agg, h, pre, Wt + 0*16384,
                                  sg + 0, sb + 0, l2g + 0, l2b + 0,
                                  l1g + 1*64, l1b + 1*64, 0, 1);
  k_pool8<<<NG*8, 256, 0, stream>>>(agg, goff, pooled + 1*32768);

  // layers 1,2
  for (int i = 1; i < 3; ++i){
    k_aggregate<<<12500, 256, 0, stream>>>(pre, off, csr, agg);
    int wp = (i < 2) ? 1 : 0;
    k_sab<<<3125, 256, 0, stream>>>(agg, h, pre, Wt + i*16384,
                                    sg + i*64, sb + i*64, l2g + i*64, l2b + i*64,
                                    l1g + (i+1)*64, l1b + (i+1)*64, 1, wp);
    k_pool8<<<NG*8, 256, 0, stream>>>(agg, goff, pooled + (i+1)*32768);
  }

  k_final<<<32, 256, 0, stream>>>(pooled, Wp, bp, out);
}

// Round 4
// 670.397 us; speedup vs baseline: 1.3650x; 1.0425x over previous
//
#include <hip/hip_runtime.h>

#define NN 50000
#define NE 800000
#define NG 128
#define RREP 16
#define RSTRIDE 50048

typedef __attribute__((ext_vector_type(8))) short short8;
typedef __attribute__((ext_vector_type(4))) float f32x4;

__device__ __forceinline__ unsigned short f2bf(float f){
  union { float f; unsigned int u; } v; v.f = f;
  return (unsigned short)((v.u + 0x7fffu + ((v.u >> 16) & 1u)) >> 16);
}
__device__ __forceinline__ float bf2f(unsigned short h){
  union { unsigned int u; float f; } v; v.u = ((unsigned int)h) << 16;
  return v.f;
}

// ---------------- graph offsets from SORTED graph_ids: boundary scan, zero atomics ----------------
__global__ __launch_bounds__(256) void k_goff(const int* __restrict__ gid,
                                              int* __restrict__ goff){
  int i = blockIdx.x*256 + threadIdx.x;
  if (i >= NN) return;
  int c = gid[i];
  int p = (i == 0) ? -1 : gid[i-1];
  for (int g = p+1; g <= c; ++g) goff[g] = i;
  if (i == NN-1){
    for (int g = c+1; g <= NG; ++g) goff[g] = NN;
  }
}

// ---------------- CSR build (16-way replicated histograms to kill atomic line contention) ----------------
__global__ __launch_bounds__(256) void k_count_rep(const int* __restrict__ idx,
                                                   int* __restrict__ cnt_rep, int n){
  int i = blockIdx.x*256 + threadIdx.x;
  int r = blockIdx.x & (RREP-1);
  if (i < n) atomicAdd(&cnt_rep[r*RSTRIDE + idx[i]], 1);
}

__global__ __launch_bounds__(256) void k_reduce_rep(const int* __restrict__ cnt_rep,
                                                    int* __restrict__ cnt){
  int i = blockIdx.x*256 + threadIdx.x;
  if (i < NN){
    int s = 0;
    #pragma unroll
    for (int r=0; r<RREP; ++r) s += cnt_rep[r*RSTRIDE + i];
    cnt[i] = s;
  }
}

__global__ __launch_bounds__(256) void k_blocksum(const int* __restrict__ in, int n,
                                                  int* __restrict__ bsum){
  __shared__ int ws4[4];
  int i = blockIdx.x*256 + threadIdx.x;
  int v = (i < n) ? in[i] : 0;
  #pragma unroll
  for (int d=1; d<64; d<<=1) v += __shfl_xor(v, d);
  int lane = threadIdx.x & 63, w = threadIdx.x >> 6;
  if (lane == 0) ws4[w] = v;
  __syncthreads();
  if (threadIdx.x == 0) bsum[blockIdx.x] = ws4[0]+ws4[1]+ws4[2]+ws4[3];
}

// exclusive scan of n<=256 elements, single block of 256; out[n]=total
__global__ __launch_bounds__(256) void k_scan_small(const int* __restrict__ in, int n,
                                                    int* __restrict__ out){
  __shared__ int wsum[4];
  int tid = threadIdx.x, lane = tid & 63, w = tid >> 6;
  int v = (tid < n) ? in[tid] : 0;
  int x = v;
  #pragma unroll
  for (int d=1; d<64; d<<=1){ int y = __shfl_up(x, d); if (lane >= d) x += y; }
  if (lane == 63) wsum[w] = x;
  __syncthreads();
  int pre2 = 0;
  for (int j=0; j<w; ++j) pre2 += wsum[j];
  int incl = x + pre2;
  if (tid < n) out[tid] = incl - v;
  if (tid == n-1) out[n] = incl;
}

__global__ __launch_bounds__(256) void k_scan_apply(const int* __restrict__ in, int n,
                                                    const int* __restrict__ boff,
                                                    int* __restrict__ out){
  __shared__ int wsum[4];
  int tid = threadIdx.x, lane = tid & 63, w = tid >> 6;
  int i = blockIdx.x*256 + tid;
  int v = (i < n) ? in[i] : 0;
  int x = v;
  #pragma unroll
  for (int d=1; d<64; d<<=1){ int y = __shfl_up(x, d); if (lane >= d) x += y; }
  if (lane == 63) wsum[w] = x;
  __syncthreads();
  int pre2 = boff[blockIdx.x];
  for (int j=0; j<w; ++j) pre2 += wsum[j];
  int excl = x - v + pre2;
  if (i < n){
    out[i] = excl;
    if (i == n-1) out[n] = excl + v;
  }
}

// per-replica fill cursors: fpos_rep[r][n] = off[n] + sum_{j<r} cnt_rep[j][n]
__global__ __launch_bounds__(256) void k_fpos_rep(const int* __restrict__ cnt_rep,
                                                  const int* __restrict__ off,
                                                  int* __restrict__ fpos_rep){
  int i = blockIdx.x*256 + threadIdx.x;
  if (i < NN){
    int p = off[i];
    #pragma unroll
    for (int r=0; r<RREP; ++r){
      fpos_rep[r*RSTRIDE + i] = p;
      p += cnt_rep[r*RSTRIDE + i];
    }
  }
}

__global__ __launch_bounds__(256) void k_fill_rep(const int* __restrict__ src,
                                                  const int* __restrict__ dst,
                                                  int* __restrict__ fpos_rep,
                                                  int* __restrict__ csr, int n){
  int i = blockIdx.x*256 + threadIdx.x;
  int r = blockIdx.x & (RREP-1);
  if (i < n){
    int p = atomicAdd(&fpos_rep[r*RSTRIDE + dst[i]], 1);
    csr[p] = src[i];
  }
}

// ---------------- weight pre-transpose to bf16 ----------------
// Wt layout per layer: [256 rows][64 k] bf16; rows 0..63=q cols, 64..127=k, 128..191=v, 192..255=o
__global__ __launch_bounds__(256) void k_wt(const float* __restrict__ Wq,
                                            const float* __restrict__ Wk,
                                            const float* __restrict__ Wv,
                                            const float* __restrict__ Wo,
                                            unsigned short* __restrict__ Wt){
  int gid = blockIdx.x*256 + threadIdx.x;   // 49152 total
  int l   = gid >> 14;
  int rem = gid & 16383;
  int mat = rem >> 12;
  int idx = rem & 4095;
  int c = idx >> 6, n = idx & 63;
  const float* srcp = (mat==0)?Wq:(mat==1)?Wk:(mat==2)?Wv:Wo;
  float v = srcp[l*4096 + idx];
  Wt[l*16384 + (mat*64 + n)*64 + c] = f2bf(v);
}

// ---------------- elementwise fp32 -> bf16 ----------------
__global__ __launch_bounds__(256) void k_f2bf(const float* __restrict__ in,
                                              unsigned short* __restrict__ out){
  int i = blockIdx.x*256 + threadIdx.x;   // one ushort4 per thread
  float4 v = ((const float4*)in)[i];
  ushort4 o; o.x=f2bf(v.x); o.y=f2bf(v.y); o.z=f2bf(v.z); o.w=f2bf(v.w);
  ((ushort4*)out)[i] = o;
}

// ---------------- GIN aggregate via CSR gather (bf16 table, fp32 accum, bf16 out) ----------------
__global__ __launch_bounds__(256) void k_aggregate(const unsigned short* __restrict__ pre,
                                                   const int* __restrict__ off,
                                                   const int* __restrict__ csr,
                                                   unsigned short* __restrict__ agg){
  int w = threadIdx.x >> 6, lane = threadIdx.x & 63;
  int node = blockIdx.x*4 + w;
  int s = off[node], e = off[node+1];
  const ushort4* base = (const ushort4*)pre;
  ushort4 u = base[node*64 + lane];
  float a0 = bf2f(u.x), a1 = bf2f(u.y), a2 = bf2f(u.z), a3 = bf2f(u.w);
  int i = s;
  for (; i + 4 <= e; i += 4){
    int n0 = csr[i], n1 = csr[i+1], n2 = csr[i+2], n3 = csr[i+3];
    ushort4 u0 = base[n0*64 + lane], u1 = base[n1*64 + lane];
    ushort4 u2 = base[n2*64 + lane], u3 = base[n3*64 + lane];
    a0 += bf2f(u0.x)+bf2f(u1.x)+bf2f(u2.x)+bf2f(u3.x);
    a1 += bf2f(u0.y)+bf2f(u1.y)+bf2f(u2.y)+bf2f(u3.y);
    a2 += bf2f(u0.z)+bf2f(u1.z)+bf2f(u2.z)+bf2f(u3.z);
    a3 += bf2f(u0.w)+bf2f(u1.w)+bf2f(u2.w)+bf2f(u3.w);
  }
  for (; i < e; ++i){
    int n0 = csr[i];
    ushort4 u0 = base[n0*64 + lane];
    a0 += bf2f(u0.x); a1 += bf2f(u0.y); a2 += bf2f(u0.z); a3 += bf2f(u0.w);
  }
  ushort4 o; o.x=f2bf(a0); o.y=f2bf(a1); o.z=f2bf(a2); o.w=f2bf(a3);
  ((ushort4*)agg)[node*64 + lane] = o;
}

// ---------------- fused SAB: LN -> QKV (MFMA) -> attn(S=4) -> O-proj (MFMA) -> residual
//                  -> epilogue: write h (bf16), relu+LN2 -> lnout (bf16, into agg), LN1 -> bf16 pre_next
// one wave = 4 nodes = 16 rows; block = 4 waves = 16 nodes; grid = 3125. Wave-private LDS, no __syncthreads.
// NOTE qkv_s row stride 200 ushorts: must be mult of 8 (16B align for ds_*_b128); among those,
// 4-row bank distance mod 32 can only be 0 or 16 -> 200 (=16) is optimal, 4-way conflicts unavoidable.
__global__ __launch_bounds__(256) void k_sab(unsigned short* __restrict__ agg,
                                             unsigned short* __restrict__ h,
                                             unsigned short* __restrict__ pre_next,
                                             const unsigned short* __restrict__ Wt,
                                             const float* __restrict__ lng,
                                             const float* __restrict__ lnb,
                                             const float* __restrict__ g2,
                                             const float* __restrict__ b2,
                                             const float* __restrict__ g1,
                                             const float* __restrict__ b1,
                                             int residual, int write_pre, int write_h){
  __shared__ unsigned short xo_s[4][16][72];    // xin (phase1/2) then o (phase3/4), aliased
  __shared__ unsigned short qkv_s[4][16][200];  // cols 0..63 q, 64..127 k, 128..191 v

  int tid = threadIdx.x;
  int w = tid >> 6, lane = tid & 63;
  int c16 = lane & 15, kb = lane >> 4;
  int R0 = blockIdx.x*64 + w*16;   // 16 contiguous global rows (4 nodes)

  // phase 1: LN of agg rows (bf16 in) -> bf16 staging
  {
    float4 gv = ((const float4*)lng)[c16];
    float4 bv = ((const float4*)lnb)[c16];
    #pragma unroll
    for (int rr=0; rr<4; ++rr){
      int m = rr*4 + kb;
      ushort4 uv = ((const ushort4*)agg)[(R0+m)*16 + c16];
      float vx = bf2f(uv.x), vy = bf2f(uv.y), vz = bf2f(uv.z), vw = bf2f(uv.w);
      float s = vx+vy+vz+vw;
      float q = vx*vx+vy*vy+vz*vz+vw*vw;
      #pragma unroll
      for (int d=1; d<16; d<<=1){ s += __shfl_xor(s, d); q += __shfl_xor(q, d); }
      float mu = s*(1.f/64.f);
      float rs = rsqrtf(q*(1.f/64.f) - mu*mu + 1e-5f);
      ushort4 o;
      o.x=f2bf((vx-mu)*rs*gv.x+bv.x); o.y=f2bf((vy-mu)*rs*gv.y+bv.y);
      o.z=f2bf((vz-mu)*rs*gv.z+bv.z); o.w=f2bf((vw-mu)*rs*gv.w+bv.w);
      *(ushort4*)&xo_s[w][m][c16*4] = o;
    }
  }

  // phase 2: QKV = xin @ Wqkv
  short8 a0 = *(const short8*)&xo_s[w][c16][kb*8];
  short8 a1 = *(const short8*)&xo_s[w][c16][32 + kb*8];
  f32x4 acc[12];
  #pragma unroll
  for (int t=0; t<12; ++t){
    short8 b0 = *(const short8*)&Wt[(t*16 + c16)*64 + kb*8];
    short8 b1 = *(const short8*)&Wt[(t*16 + c16)*64 + 32 + kb*8];
    f32x4 z = {0.f, 0.f, 0.f, 0.f};
    z = __builtin_amdgcn_mfma_f32_16x16x32_bf16(a0, b0, z, 0, 0, 0);
    z = __builtin_amdgcn_mfma_f32_16x16x32_bf16(a1, b1, z, 0, 0, 0);
    acc[t] = z;
  }
  // C/D layout: col=lane&15, row=(lane>>4)*4+reg
  #pragma unroll
  for (int t=0; t<12; ++t){
    #pragma unroll
    for (int r=0; r<4; ++r)
      qkv_s[w][kb*4 + r][t*16 + c16] = f2bf(acc[t][r]);
  }

  // phase 3: attention, S=4, per (node, head, q-row) lane
  {
    int p = lane >> 2, qr = lane & 3;
    int ns = p >> 2, hd = p & 3;
    int mrow = ns*4 + qr;
    int qc = hd*16, kc = 64 + hd*16, vc = 128 + hd*16;
    float qv[16];
    short8 u0 = *(const short8*)&qkv_s[w][mrow][qc];
    short8 u1 = *(const short8*)&qkv_s[w][mrow][qc+8];
    #pragma unroll
    for (int j=0; j<8; ++j){
      qv[j]   = bf2f((unsigned short)u0[j]);
      qv[8+j] = bf2f((unsigned short)u1[j]);
    }
    float sc[4];
    #pragma unroll
    for (int kr=0; kr<4; ++kr){
      short8 k0 = *(const short8*)&qkv_s[w][ns*4+kr][kc];
      short8 k1 = *(const short8*)&qkv_s[w][ns*4+kr][kc+8];
      float d2 = 0.f;
      #pragma unroll
      for (int j=0; j<8; ++j){
        d2 += qv[j]  *bf2f((unsigned short)k0[j]);
        d2 += qv[8+j]*bf2f((unsigned short)k1[j]);
      }
      sc[kr] = d2 * 0.25f;   // 1/sqrt(16)
    }
    float mx = fmaxf(fmaxf(sc[0],sc[1]), fmaxf(sc[2],sc[3]));
    float e0=__expf(sc[0]-mx), e1=__expf(sc[1]-mx), e2=__expf(sc[2]-mx), e3=__expf(sc[3]-mx);
    float inv = 1.f/(e0+e1+e2+e3);
    float at[4] = {e0*inv, e1*inv, e2*inv, e3*inv};
    float ov[16];
    #pragma unroll
    for (int j=0; j<16; ++j) ov[j] = 0.f;
    #pragma unroll
    for (int kr=0; kr<4; ++kr){
      short8 v0 = *(const short8*)&qkv_s[w][ns*4+kr][vc];
      short8 v1 = *(const short8*)&qkv_s[w][ns*4+kr][vc+8];
      #pragma unroll
      for (int j=0; j<8; ++j){
        ov[j]   += at[kr]*bf2f((unsigned short)v0[j]);
        ov[8+j] += at[kr]*bf2f((unsigned short)v1[j]);
      }
    }
    short8 s0v, s1v;
    #pragma unroll
    for (int j=0; j<8; ++j){
      s0v[j] = (short)f2bf(ov[j]);
      s1v[j] = (short)f2bf(ov[8+j]);
    }
    *(short8*)&xo_s[w][mrow][qc]   = s0v;
    *(short8*)&xo_s[w][mrow][qc+8] = s1v;
  }

  // phase 4: val = o @ Wo (+ h + agg if residual)
  short8 oa0 = *(const short8*)&xo_s[w][c16][kb*8];
  short8 oa1 = *(const short8*)&xo_s[w][c16][32 + kb*8];
  float val[4][4];   // [t][r]: row kb*4+r, col t*16+c16
  #pragma unroll
  for (int t=0; t<4; ++t){
    short8 b0 = *(const short8*)&Wt[(192 + t*16 + c16)*64 + kb*8];
    short8 b1 = *(const short8*)&Wt[(192 + t*16 + c16)*64 + 32 + kb*8];
    f32x4 z = {0.f, 0.f, 0.f, 0.f};
    z = __builtin_amdgcn_mfma_f32_16x16x32_bf16(oa0, b0, z, 0, 0, 0);
    z = __builtin_amdgcn_mfma_f32_16x16x32_bf16(oa1, b1, z, 0, 0, 0);
    #pragma unroll
    for (int r=0; r<4; ++r){
      float v = z[r];
      if (residual){
        int gi = (R0 + kb*4 + r)*64 + t*16 + c16;
        v += bf2f(h[gi]) + bf2f(agg[gi]);
      }
      val[t][r] = v;
    }
  }

  // epilogue: per-row stats for LN1 (raw) and LN2 (relu), 16-lane reductions
  float s1[4], q1[4], s2[4], q2[4];
  #pragma unroll
  for (int r=0; r<4; ++r){
    float a=0.f, b=0.f, c=0.f, d=0.f;
    #pragma unroll
    for (int t=0; t<4; ++t){
      float v = val[t][r];
      float rv = fmaxf(v, 0.f);
      a += v; b += v*v; c += rv; d += rv*rv;
    }
    s1[r]=a; q1[r]=b; s2[r]=c; q2[r]=d;
  }
  #pragma unroll
  for (int d=1; d<16; d<<=1){
    #pragma unroll
    for (int r=0; r<4; ++r){
      s1[r] += __shfl_xor(s1[r], d); q1[r] += __shfl_xor(q1[r], d);
      s2[r] += __shfl_xor(s2[r], d); q2[r] += __shfl_xor(q2[r], d);
    }
  }
  float mu1[4], rs1[4], mu2[4], rs2[4];
  #pragma unroll
  for (int r=0; r<4; ++r){
    mu1[r] = s1[r]*(1.f/64.f);
    rs1[r] = rsqrtf(q1[r]*(1.f/64.f) - mu1[r]*mu1[r] + 1e-5f);
    mu2[r] = s2[r]*(1.f/64.f);
    rs2[r] = rsqrtf(q2[r]*(1.f/64.f) - mu2[r]*mu2[r] + 1e-5f);
  }
  #pragma unroll
  for (int t=0; t<4; ++t){
    int col = t*16 + c16;
    float g2v = g2[col], b2v = b2[col];
    float g1v = 0.f, b1v = 0.f;
    if (write_pre){ g1v = g1[col]; b1v = b1[col]; }
    #pragma unroll
    for (int r=0; r<4; ++r){
      int gi = (R0 + kb*4 + r)*64 + col;
      float v = val[t][r];
      if (write_h) h[gi] = f2bf(v);
      float rv = fmaxf(v, 0.f);
      agg[gi] = f2bf((rv - mu2[r])*rs2[r]*g2v + b2v);   // lnout for pooling (overwrites agg)
      if (write_pre)
        pre_next[gi] = f2bf((v - mu1[r])*rs1[r]*g1v + b1v);
    }
  }
}

// ---------------- per-graph pooling: 8 sub-blocks per graph, atomic merge ----------------
__global__ __launch_bounds__(256) void k_pool8(const float* __restrict__ src,
                                               const int* __restrict__ goff,
                                               float* __restrict__ out){
  int g = blockIdx.x >> 3, sub = blockIdx.x & 7, t = threadIdx.x;
  int s = goff[g], e = goff[g+1], len = e - s;
  int s0 = s + ((len*sub) >> 3), e0 = s + ((len*(sub+1)) >> 3);
  float a0=0.f, a1=0.f;
  int n = s0;
  for (; n + 2 <= e0; n += 2){ a0 += src[n*256 + t]; a1 += src[(n+1)*256 + t]; }
  if (n < e0) a0 += src[n*256 + t];
  atomicAdd(&out[g*256 + t], a0 + a1);
}

__global__ __launch_bounds__(256) void k_pool8b(const unsigned short* __restrict__ src,
                                                const int* __restrict__ goff,
                                                float* __restrict__ out){
  int g = blockIdx.x >> 3, sub = blockIdx.x & 7, t = threadIdx.x;
  int s = goff[g], e = goff[g+1], len = e - s;
  int s0 = s + ((len*sub) >> 3), e0 = s + ((len*(sub+1)) >> 3);
  float a0=0.f, a1=0.f;
  int n = s0;
  for (; n + 2 <= e0; n += 2){ a0 += bf2f(src[n*256 + t]); a1 += bf2f(src[(n+1)*256 + t]); }
  if (n < e0) a0 += bf2f(src[n*256 + t]);
  atomicAdd(&out[g*256 + t], a0 + a1);
}

// ---------------- final: score = sum_i pooled_i @ W_pred[i] + b_pred[i] ----------------
__global__ __launch_bounds__(256) void k_final(const float* __restrict__ pooled,
                                               const float* __restrict__ Wp,
                                               const float* __restrict__ bp,
                                               float* __restrict__ out){
  int t = blockIdx.x*256 + threadIdx.x;  // 8192 = 128*4*16
  int b = t >> 6, s = (t >> 4) & 3, o = t & 15;
  float acc = 0.f;
  for (int i=0; i<4; ++i){
    acc += bp[i*16 + o];
    const float* pr = pooled + i*32768 + b*256 + s*64;
    const float* wp = Wp + i*1024 + o;
    float a = 0.f;
    #pragma unroll 8
    for (int c=0; c<64; ++c) a += pr[c]*wp[c*16];
    acc += a;
  }
  out[t] = acc;
}

// ---------------- workspace layout (bytes) ----------------
static const size_t OFF_H    = 0;           // bf16 [50000*256]; cnt_rep/fpos_rep alias here during build
static const size_t OFF_AGG  = 25600000;    // bf16 [50000*256] (becomes lnout after SAB)
static const size_t OFF_PRE  = 51200000;    // bf16 [50000*256]
static const size_t OFF_CSR  = 76800000;    // int [800000]
static const size_t OFF_CNT  = 80000000;    // int [50000]
static const size_t OFF_OFF  = 80200064;    // int [50001]
static const size_t OFF_GOFF = 80400128;    // int [129]
static const size_t OFF_POOL = 80400704;    // fp32 [4][128*256]
static const size_t OFF_WT   = 80924992;    // bf16 [3][256*64]
static const size_t OFF_BSUM = 81023296;    // int [196]
static const size_t OFF_BOFF = 81024128;    // int [197]

extern "C" void kernel_launch(void* const* d_in, const int* in_sizes, int n_in,
                              void* d_out, int out_size, void* d_ws, size_t ws_size,
                              hipStream_t stream) {
  const float* feat = (const float*)d_in[0];
  const int*   src  = (const int*)d_in[1];
  const int*   dst  = (const int*)d_in[2];
  const int*   gid  = (const int*)d_in[3];
  const float* Wq   = (const float*)d_in[4];
  const float* Wk   = (const float*)d_in[5];
  const float* Wv   = (const float*)d_in[6];
  const float* Wo   = (const float*)d_in[7];
  const float* sg   = (const float*)d_in[8];
  const float* sb   = (const float*)d_in[9];
  const float* l1g  = (const float*)d_in[10];
  const float* l1b  = (const float*)d_in[11];
  const float* l2g  = (const float*)d_in[12];
  const float* l2b  = (const float*)d_in[13];
  const float* Wp   = (const float*)d_in[14];
  const float* bp   = (const float*)d_in[15];
  float* out = (float*)d_out;

  char* ws = (char*)d_ws;
  unsigned short* h      = (unsigned short*)(ws + OFF_H);
  unsigned short* agg    = (unsigned short*)(ws + OFF_AGG);
  unsigned short* pre    = (unsigned short*)(ws + OFF_PRE);
  int*            csr    = (int*)(ws + OFF_CSR);
  int*            cnt    = (int*)(ws + OFF_CNT);
  int*            off    = (int*)(ws + OFF_OFF);
  int*            goff   = (int*)(ws + OFF_GOFF);
  float*          pooled = (float*)(ws + OFF_POOL);
  unsigned short* Wt     = (unsigned short*)(ws + OFF_WT);
  int*            bsum   = (int*)(ws + OFF_BSUM);
  int*            boff   = (int*)(ws + OFF_BOFF);
  // replicated build scratch aliases the h region (h is first written by k_sab, after build)
  int*            cnt_rep  = (int*)(ws + OFF_H);
  int*            fpos_rep = (int*)(ws + OFF_H + (size_t)RREP*RSTRIDE*4);

  hipMemsetAsync(cnt_rep, 0, (size_t)RREP*RSTRIDE*4, stream);
  hipMemsetAsync(pooled, 0, 4*NG*256*sizeof(float), stream);

  // CSR for dst (replicated histograms); graph offsets via sorted-boundary scan
  k_count_rep<<<NE/256, 256, 0, stream>>>(dst, cnt_rep, NE);
  k_goff<<<(NN+255)/256, 256, 0, stream>>>(gid, goff);
  k_reduce_rep<<<(NN+255)/256, 256, 0, stream>>>(cnt_rep, cnt);
  k_blocksum<<<196, 256, 0, stream>>>(cnt, NN, bsum);
  k_scan_small<<<1, 256, 0, stream>>>(bsum, 196, boff);
  k_scan_apply<<<196, 256, 0, stream>>>(cnt, NN, boff, off);
  k_fpos_rep<<<(NN+255)/256, 256, 0, stream>>>(cnt_rep, off, fpos_rep);
  k_fill_rep<<<NE/256, 256, 0, stream>>>(src, dst, fpos_rep, csr, NE);

  // weights transpose + feat->bf16 + hidden_rep[0] pooling
  k_wt<<<192, 256, 0, stream>>>(Wq, Wk, Wv, Wo, Wt);
  k_f2bf<<<12500, 256, 0, stream>>>(feat, pre);
  k_pool8<<<NG*8, 256, 0, stream>>>(feat, goff, pooled + 0*32768);

  // layer 0: agg = feat + segsum(feat[src]); h = SAB(agg); fused relu+LN2 -> agg, LN1(i=1) -> pre
  k_aggregate<<<12500, 256, 0, stream>>>(pre, off, csr, agg);
  k_sab<<<3125, 256, 0, stream>>>(agg, h, pre, Wt + 0*16384,
                                  sg + 0, sb + 0, l2g + 0, l2b + 0,
                                  l1g + 1*64, l1b + 1*64, 0, 1, 1);
  k_pool8b<<<NG*8, 256, 0, stream>>>(agg, goff, pooled + 1*32768);

  // layers 1,2
  for (int i = 1; i < 3; ++i){
    k_aggregate<<<12500, 256, 0, stream>>>(pre, off, csr, agg);
    int wp = (i < 2) ? 1 : 0;
    int wh = (i < 2) ? 1 : 0;   // layer 2's h is never read again
    k_sab<<<3125, 256, 0, stream>>>(agg, h, pre, Wt + i*16384,
                                    sg + i*64, sb + i*64, l2g + i*64, l2b + i*64,
                                    l1g + (i+1)*64, l1b + (i+1)*64, 1, wp, wh);
    k_pool8b<<<NG*8, 256, 0, stream>>>(agg, goff, pooled + (i+1)*32768);
  }

  k_final<<<32, 256, 0, stream>>>(pooled, Wp, bp, out);
}